// Round 13
// baseline (218.255 us; speedup 1.0000x reference)
//
#include <hip/hip_runtime.h>
#include <hip/hip_bf16.h>
#include <math.h>

#define EPSF 1e-5f
#define SELHI 0x05040100u
#define SELLO 0x07060302u

typedef __attribute__((ext_vector_type(8))) short bf16x8;
typedef __attribute__((ext_vector_type(16))) float f32x16;

// pack float -> u32 { low16 = hi-bf16 (truncated), high16 = lo-bf16 (residual) }
__device__ __forceinline__ uint32_t packsplit(float x) {
  uint32_t xb = __builtin_bit_cast(uint32_t, x);
  float hi = __builtin_bit_cast(float, xb & 0xFFFF0000u);
  float resid = x - hi;
  return __builtin_amdgcn_perm(__builtin_bit_cast(uint32_t, resid), xb, 0x07060302u);
}

// float -> bf16 round-to-nearest-even (16-bit value in low bits)
__device__ __forceinline__ uint32_t bf16rne(float x) {
  uint32_t xb = __builtin_bit_cast(uint32_t, x);
  return (xb + 0x7FFFu + ((xb >> 16) & 1u)) >> 16;
}

__device__ __forceinline__ uint4 mkfrag8(const uint32_t* p, uint32_t sel) {
  uint4 u;
  u.x = __builtin_amdgcn_perm(p[1], p[0], sel);
  u.y = __builtin_amdgcn_perm(p[3], p[2], sel);
  u.z = __builtin_amdgcn_perm(p[5], p[4], sel);
  u.w = __builtin_amdgcn_perm(p[7], p[6], sel);
  return u;
}

__device__ __forceinline__ f32x16 mf(uint4 a, uint4 b, f32x16 c) {
  return __builtin_amdgcn_mfma_f32_32x32x16_bf16(
      __builtin_bit_cast(bf16x8, a), __builtin_bit_cast(bf16x8, b), c, 0, 0, 0);
}

#define F4C(v, i) ((i) == 0 ? (v).x : (i) == 1 ? (v).y : (i) == 2 ? (v).z : (v).w)

// =====================================================================
// Kernel 0: qa fragment precompute (batch-independent, 512 KB, once).
// =====================================================================
__global__ __launch_bounds__(64) void qa_pack_kernel(
    const float* __restrict__ addresses, uint32_t* __restrict__ qaF)
{
  const int T = blockIdx.x;
  const int lane = threadIdx.x;
  const int g32 = lane >> 5, c32 = lane & 31;
  #pragma unroll
  for (int ks = 0; ks < 4; ++ks) {
    const float* ap = addresses + (size_t)(T*32 + c32)*64 + ks*16 + g32*8;
    float4 f0 = *(const float4*)ap;
    float4 f1 = *(const float4*)(ap + 4);
    uint32_t qp[8] = {
      packsplit(fmaxf(f0.x,0.f)), packsplit(fmaxf(f0.y,0.f)),
      packsplit(fmaxf(f0.z,0.f)), packsplit(fmaxf(f0.w,0.f)),
      packsplit(fmaxf(f1.x,0.f)), packsplit(fmaxf(f1.y,0.f)),
      packsplit(fmaxf(f1.z,0.f)), packsplit(fmaxf(f1.w,0.f)) };
    *(uint4*)&qaF[(size_t)T*2048 + (ks*2+0)*256 + lane*4] = mkfrag8(qp, SELHI);
    *(uint4*)&qaF[(size_t)T*2048 + (ks*2+1)*256 + lane*4] = mkfrag8(qp, SELLO);
  }
}

// =====================================================================
// Kernel 1: fused projection GEMM (unchanged)
// =====================================================================
__global__ __launch_bounds__(256) void proj_gemm_kernel(
    const float* __restrict__ x,
    const float* __restrict__ Wk, const float* __restrict__ bk,
    const float* __restrict__ Wv, const float* __restrict__ bv,
    const float* __restrict__ Wq, const float* __restrict__ bq,
    float* __restrict__ proj)
{
  __shared__ float As[16][68];
  __shared__ float Bs[16][68];
  const int col0 = blockIdx.x * 64;
  const int row0 = blockIdx.y * 64;
  const float* Bp; const float* bias; int ldb, bcol, relu;
  if (col0 < 512)       { Bp = Wk; bias = bk; ldb = 512;  bcol = col0;        relu = 1; }
  else if (col0 < 1536) { Bp = Wv; bias = bv; ldb = 1024; bcol = col0 - 512;  relu = 0; }
  else                  { Bp = Wq; bias = bq; ldb = 512;  bcol = col0 - 1536; relu = 1; }
  const int tid = threadIdx.x;
  const int tr = tid >> 4, tc = tid & 15;
  float acc[4][4] = {};
  for (int k0 = 0; k0 < 1024; k0 += 16) {
    {
      int r = tid >> 2, kk = (tid & 3) << 2;
      float4 a4 = *(const float4*)&x[(size_t)(row0 + r) * 1024 + k0 + kk];
      As[kk+0][r] = a4.x; As[kk+1][r] = a4.y; As[kk+2][r] = a4.z; As[kk+3][r] = a4.w;
    }
    {
      int kr = tid >> 4, cc = (tid & 15) << 2;
      *(float4*)&Bs[kr][cc] = *(const float4*)&Bp[(size_t)(k0 + kr) * ldb + bcol + cc];
    }
    __syncthreads();
    #pragma unroll
    for (int k = 0; k < 16; ++k) {
      float4 av4 = *(const float4*)&As[k][tr*4];
      float4 bv4 = *(const float4*)&Bs[k][tc*4];
      float av[4] = {av4.x, av4.y, av4.z, av4.w};
      float bb[4] = {bv4.x, bv4.y, bv4.z, bv4.w};
      #pragma unroll
      for (int i = 0; i < 4; ++i)
        #pragma unroll
        for (int j = 0; j < 4; ++j)
          acc[i][j] = fmaf(av[i], bb[j], acc[i][j]);
    }
    __syncthreads();
  }
  #pragma unroll
  for (int i = 0; i < 4; ++i) {
    int r = row0 + tr*4 + i;
    #pragma unroll
    for (int j = 0; j < 4; ++j) {
      int cl = tc*4 + j;
      float v = acc[i][j] + bias[bcol + cl];
      if (relu) v = fmaxf(v, 0.f);
      proj[(size_t)r * 2048 + col0 + cl] = v;
    }
  }
}

// =====================================================================
// Kernel 2: fused memory kernel, R12 = R11 body + batch split 2x.
//   grid 1024: block = (batch b, half). Each wave: 256 m-rows, 8
//   supersteps. matrix2/norm2 written as per-block partials to ws;
//   num2/den2/attn moved to attn_epilogue_kernel. Main-loop body and
//   register footprint byte-identical to R11 (no-spill preserved).
//   LDS 51.2 KB -> 3 blocks/CU now reachable with grid 1024.
// =====================================================================
__global__ __launch_bounds__(256, 2) void fused_mem_kernel(
    const float* __restrict__ memories,   // [512][2048][64]
    const float* __restrict__ addresses,  // [2048][64]
    const float* __restrict__ proj,       // [512][2048] = fk|v|fq
    const uint32_t* __restrict__ qaF,     // [64][8][64][4] qa fragments
    float* __restrict__ m2part,           // [1024][64][64] partials
    float* __restrict__ n2part)           // [1024][64]
{
  // 51.2 KB arena:
  //  [0,2048)      fkFrag   (epilogue: n2stage overlay)
  //  [2048,4096)   vFrag
  //  [4096,12800)  pk region: 4 waves x { pF16[32][68], pN16[32][68] } ushort
  __shared__ uint32_t SH[12800];

  const int bh = blockIdx.x;
  const int b = bh >> 1, half = bh & 1;
  const int tid = threadIdx.x;
  const int wave = tid >> 6, lane = tid & 63;
  const int g32 = lane >> 5, c32 = lane & 31;

  uint32_t* fkFrag = SH;
  uint32_t* vFrag  = SH + 2048;
  uint32_t* pkbase = SH + 4096;
  unsigned short* pF16 = (unsigned short*)(pkbase + wave * 2176);  // [32][68]
  unsigned short* pN16 = pF16 + 2176;

  // ---- stage proj row (pbuf overlays pk region) ----
  float* pbuf = (float*)pkbase;
  {
    const float* prow = proj + (size_t)b * 2048;
    *(float4*)&pbuf[tid*8]   = *(const float4*)&prow[tid*8];
    *(float4*)&pbuf[tid*8+4] = *(const float4*)&prow[tid*8+4];
  }
  __syncthreads();

  // ---- one-time fragment packing (wave w: kstep w, e-tile w) ----
  {
    const int ks = wave;
    float4 f0 = *(const float4*)&pbuf[c32*64 + ks*16 + g32*8];
    float4 f1 = *(const float4*)&pbuf[c32*64 + ks*16 + g32*8 + 4];
    uint32_t p[8] = { packsplit(f0.x), packsplit(f0.y), packsplit(f0.z), packsplit(f0.w),
                      packsplit(f1.x), packsplit(f1.y), packsplit(f1.z), packsplit(f1.w) };
    *(uint4*)&fkFrag[((ks*2+0)*64 + lane)*4] = mkfrag8(p, SELHI);
    *(uint4*)&fkFrag[((ks*2+1)*64 + lane)*4] = mkfrag8(p, SELLO);
    const int t = wave;
    uint32_t q[8];
    #pragma unroll
    for (int j = 0; j < 8; ++j) {
      int h = (g32*8 + j) & 7;
      q[j] = packsplit(pbuf[512 + h*128 + t*32 + c32]);
    }
    *(uint4*)&vFrag[((t*2+0)*64 + lane)*4] = mkfrag8(q, SELHI);
    *(uint4*)&vFrag[((t*2+1)*64 + lane)*4] = mkfrag8(q, SELLO);
  }
  __syncthreads();

  f32x16 Zv;
  #pragma unroll
  for (int r = 0; r < 16; ++r) Zv[r] = 0.f;
  f32x16 aD00 = Zv, aD01 = Zv, aD10 = Zv, aD11 = Zv;
  float n2a[32];
  #pragma unroll
  for (int k = 0; k < 32; ++k) n2a[k] = 0.f;

  const int T0 = half*32 + wave*8;                       // first 32-row tile
  const float* aRow0 = addresses + (size_t)(T0*32 + c32) * 64;
  const float* mRow0 = memories + ((size_t)b*2048 + T0*32 + c32) * 64;
  const uint32_t* qaBase = qaF + (size_t)T0*2048 + lane*4;

  // phase D: single-bf16 operands; 4 MFMAs per 16-row chunk.
  auto do_mfma = [&](int base) {
    uint32_t f0[4], f1[4], n0[4], n1[4];
    #pragma unroll
    for (int e = 0; e < 4; ++e) {
      const int r0 = (base + g32*8 + 2*e) * 68;
      const int r1 = r0 + 68;
      f0[e] = (uint32_t)pF16[r0 + c32]      | ((uint32_t)pF16[r1 + c32] << 16);
      f1[e] = (uint32_t)pF16[r0 + 32 + c32] | ((uint32_t)pF16[r1 + 32 + c32] << 16);
      n0[e] = (uint32_t)pN16[r0 + c32]      | ((uint32_t)pN16[r1 + c32] << 16);
      n1[e] = (uint32_t)pN16[r0 + 32 + c32] | ((uint32_t)pN16[r1 + 32 + c32] << 16);
    }
    uint4 A0 = make_uint4(f0[0], f0[1], f0[2], f0[3]);
    uint4 A1 = make_uint4(f1[0], f1[1], f1[2], f1[3]);
    uint4 B0 = make_uint4(n0[0], n0[1], n0[2], n0[3]);
    uint4 B1 = make_uint4(n1[0], n1[1], n1[2], n1[3]);
    aD00 = mf(A0, B0, aD00);
    aD01 = mf(A0, B1, aD01);
    aD10 = mf(A1, B0, aD10);
    aD11 = mf(A1, B1, aD11);
  };

#define QATAB_B(QP, ACC) do {                                          \
    _Pragma("unroll")                                                  \
    for (int ks = 0; ks < 4; ++ks) {                                   \
      uint4 qh_ = *(const uint4*)((QP) + (ks*2+0)*256);                \
      uint4 ql_ = *(const uint4*)((QP) + (ks*2+1)*256);                \
      uint4 Ah_ = *(uint4*)&fkFrag[((ks*2+0)*64 + lane)*4];            \
      uint4 Al_ = *(uint4*)&fkFrag[((ks*2+1)*64 + lane)*4];            \
      ACC = mf(Ah_, qh_, ACC); ACC = mf(Ah_, ql_, ACC); ACC = mf(Al_, qh_, ACC); \
    } } while(0)

#define ELEM(T2, ACU, ACW) do {                                        \
    unsigned short* rowF_ = pF16 + c32*68;                             \
    unsigned short* rowN_ = pN16 + c32*68;                             \
    _Pragma("unroll")                                                  \
    for (int rq = 0; rq < 4; ++rq) {                                   \
      uint32_t pf_[4], pn_[4];                                         \
      _Pragma("unroll")                                                \
      for (int i = 0; i < 4; ++i) {                                    \
        const int r = rq*4 + i;                                        \
        float upd = ACU[r];                                            \
        float wx  = ACW[r];                                            \
        float wp  = __builtin_amdgcn_rcpf(1.f + __expf(-wx));          \
        float mv  = F4C(M_[(T2)*4 + rq], i);                           \
        float av  = F4C(E_[rq & 1], i);                                \
        float nm  = fmaf(wp, upd - mv, mv);                            \
        float fv  = fmaxf(nm + av, 0.f);                               \
        n2a[(T2)*16 + r] += fv;                                        \
        pn_[i] = bf16rne(nm);                                          \
        pf_[i] = bf16rne(fv);                                          \
      }                                                                \
      if (rq == 1) { E_[0] = *(const float4*)(ap0 + (T2)*32 + 16 + g32*4);      \
                     E_[1] = *(const float4*)(ap0 + (T2)*32 + 16 + g32*4 + 8); }\
      const int col = 32*(T2) + 8*rq + 4*g32;                          \
      *(uint2*)&rowF_[col] = make_uint2(pf_[0] | (pf_[1]<<16), pf_[2] | (pf_[3]<<16)); \
      *(uint2*)&rowN_[col] = make_uint2(pn_[0] | (pn_[1]<<16), pn_[2] | (pn_[3]<<16)); \
    } } while(0)

  // ---- prologue: B(0) + M(0) ----
  f32x16 aBcur = Zv, aBnext;
  float4 M_[8];
  QATAB_B(qaBase, aBcur);
  #pragma unroll
  for (int k = 0; k < 8; ++k) M_[k] = *(const float4*)(mRow0 + k*8 + g32*4);

  #pragma unroll 1
  for (int ss = 0; ss < 8; ++ss) {
    asm volatile("" ::: "memory");

    // ---- 1. finish B(ss) ----
    float s0 = aBcur[0], s1 = aBcur[1], s2 = aBcur[2], s3 = aBcur[3];
    float own = (s0 + s1) + (s2 + s3);
    float den = own + __shfl_xor(own, 32) + EPSF;
    float rden = __builtin_amdgcn_rcpf(den);
    float p0 = __shfl_xor(s0, 32), p1 = __shfl_xor(s1, 32),
          p2 = __shfl_xor(s2, 32), p3 = __shfl_xor(s3, 32);
    float rm = (g32 == 0) ? rden : 0.f;
    uint32_t sp[8] = { packsplit(s0*rm), packsplit(s1*rm), packsplit(s2*rm), packsplit(s3*rm),
                       packsplit(p0*rm), packsplit(p1*rm), packsplit(p2*rm), packsplit(p3*rm) };
    uint4 Sh = mkfrag8(sp, SELHI), Sl = mkfrag8(sp, SELLO);

    // ---- 2. C-MFMAs, first half ----
    f32x16 aC0 = Zv, aC2 = Zv;
    {
      uint4 Vh, Vl;
      Vh = *(uint4*)&vFrag[(0*64 + lane)*4]; Vl = *(uint4*)&vFrag[(1*64 + lane)*4];
      aC0 = mf(Vh, Sh, aC0); aC0 = mf(Vh, Sl, aC0); aC0 = mf(Vl, Sh, aC0);
      Vh = *(uint4*)&vFrag[(4*64 + lane)*4]; Vl = *(uint4*)&vFrag[(5*64 + lane)*4];
      aC2 = mf(Vh, Sh, aC2); aC2 = mf(Vh, Sl, aC2); aC2 = mf(Vl, Sh, aC2);
    }

    // ---- 3. pipeline B(ss+1) ----
    aBnext = Zv;
    if (ss < 7) {
      const uint32_t* qp = qaBase + (size_t)(ss+1)*2048;
      QATAB_B(qp, aBnext);
    }

    // ---- 4. ELEM half 0 ----
    const float* ap0 = aRow0 + (size_t)ss * 2048;
    float4 E_[2];
    E_[0] = *(const float4*)(ap0 + g32*4);
    E_[1] = *(const float4*)(ap0 + g32*4 + 8);
    ELEM(0, aC0, aC2);

    // ---- 5. C-MFMAs, second half ----
    f32x16 aC1 = Zv, aC3 = Zv;
    {
      uint4 Vh, Vl;
      Vh = *(uint4*)&vFrag[(2*64 + lane)*4]; Vl = *(uint4*)&vFrag[(3*64 + lane)*4];
      aC1 = mf(Vh, Sh, aC1); aC1 = mf(Vh, Sl, aC1); aC1 = mf(Vl, Sh, aC1);
      Vh = *(uint4*)&vFrag[(6*64 + lane)*4]; Vl = *(uint4*)&vFrag[(7*64 + lane)*4];
      aC3 = mf(Vh, Sh, aC3); aC3 = mf(Vh, Sl, aC3); aC3 = mf(Vl, Sh, aC3);
    }

    // ---- 6. M_[0..3] <- ss+1 ----
    if (ss < 7) {
      const float* mp = mRow0 + (size_t)(ss+1) * 2048;
      #pragma unroll
      for (int k = 0; k < 4; ++k) M_[k] = *(const float4*)(mp + k*8 + g32*4);
    }

    // ---- 7. ELEM half 1 ----
    E_[0] = *(const float4*)(ap0 + 32 + g32*4);
    E_[1] = *(const float4*)(ap0 + 32 + g32*4 + 8);
    ELEM(1, aC1, aC3);

    // ---- 8. M_[4..7] <- ss+1 ----
    if (ss < 7) {
      const float* mp = mRow0 + (size_t)(ss+1) * 2048;
      #pragma unroll
      for (int k = 4; k < 8; ++k) M_[k] = *(const float4*)(mp + k*8 + g32*4);
    }

    // ---- 9. phase D ----
    asm volatile("" ::: "memory");
    do_mfma(0);
    do_mfma(16);

    aBcur = aBnext;
  }

  // ================= epilogue: write partials =================
  __syncthreads();

  float* n2stageF = (float*)SH;            // [4][64]
  float* stageF   = (float*)pkbase;        // [4][16][66]

  #pragma unroll
  for (int k = 0; k < 32; ++k) {
    float v = n2a[k];
    v += __shfl_xor(v, 1); v += __shfl_xor(v, 2); v += __shfl_xor(v, 4);
    v += __shfl_xor(v, 8); v += __shfl_xor(v, 16);
    n2a[k] = v;
  }
  if (c32 == 0) {
    #pragma unroll
    for (int t2 = 0; t2 < 2; ++t2)
      #pragma unroll
      for (int r = 0; r < 16; ++r) {
        const int j = 32*t2 + 8*(r>>2) + (r&3) + 4*g32;
        n2stageF[wave*64 + j] = n2a[t2*16 + r];
      }
  }
  __syncthreads();
  if (tid < 64)
    n2part[(size_t)bh*64 + tid] =
        (n2stageF[tid] + n2stageF[64+tid]) + (n2stageF[128+tid] + n2stageF[192+tid]);

  #pragma unroll
  for (int p = 0; p < 4; ++p) {
    const int ti = p >> 1, rh = p & 1;
    #pragma unroll
    for (int q = 0; q < 8; ++q) {
      const int rr = (q & 3) + 8*((q >> 2) & 1) + 4*g32;
      const int r = rh*8 + q;
      float v0 = (ti == 0) ? aD00[r] : aD10[r];
      float v1 = (ti == 0) ? aD01[r] : aD11[r];
      stageF[wave*1056 + rr*66 + c32]      = v0;
      stageF[wave*1056 + rr*66 + 32 + c32] = v1;
    }
    __syncthreads();
    {
      const int e = tid & 63, dg = tid >> 6;   // dg = 0..3
      #pragma unroll
      for (int i = 0; i < 4; ++i) {
        const int dl = dg*4 + i;
        float s = (stageF[0*1056 + dl*66 + e] + stageF[1*1056 + dl*66 + e]) +
                  (stageF[2*1056 + dl*66 + e] + stageF[3*1056 + dl*66 + e]);
        m2part[(size_t)bh*4096 + (p*16 + dl)*64 + e] = s;
      }
    }
    __syncthreads();
  }
#undef ELEM
#undef QATAB_B
}

// =====================================================================
// Kernel 2b: attn epilogue — reduce 2 partials, num2/den2, attn.
// =====================================================================
__global__ __launch_bounds__(256) void attn_epilogue_kernel(
    const float* __restrict__ m2part, const float* __restrict__ n2part,
    const float* __restrict__ proj, float* __restrict__ attn)
{
  __shared__ float fqs[512];
  __shared__ float norm2[64];
  __shared__ float den2[8];
  const int b = blockIdx.x, tid = threadIdx.x;
  const float* fqg = proj + (size_t)b * 2048 + 1536;
  *(float2*)&fqs[tid*2] = *(const float2*)&fqg[tid*2];
  if (tid < 64) norm2[tid] = n2part[(size_t)(2*b)*64 + tid] + n2part[(size_t)(2*b+1)*64 + tid];
  __syncthreads();
  if (tid < 8) {
    float s = 0.f;
    for (int d = 0; d < 64; ++d) s = fmaf(fqs[tid*64 + d], norm2[d], s);
    den2[tid] = s + EPSF;
  }
  __syncthreads();
  const int hh = tid >> 5;
  const int ee = (tid & 31) * 2;
  const float* m0 = m2part + (size_t)(2*b) * 4096;
  const float* m1 = m2part + (size_t)(2*b+1) * 4096;
  float a0 = 0.f, a1 = 0.f;
  #pragma unroll 8
  for (int d = 0; d < 64; ++d) {
    float2 u = *(const float2*)&m0[d*64 + ee];
    float2 v = *(const float2*)&m1[d*64 + ee];
    float fv = fqs[hh*64 + d];
    a0 = fmaf(fv, u.x + v.x, a0);
    a1 = fmaf(fv, u.y + v.y, a1);
  }
  float rd = __builtin_amdgcn_rcpf(den2[hh]);
  attn[(size_t)b*512 + hh*64 + ee]     = a0 * rd;
  attn[(size_t)b*512 + hh*64 + ee + 1] = a1 * rd;
}

// =====================================================================
// Kernel 3: out = attn(512x512) @ Wm(512x1024) + bm (unchanged)
// =====================================================================
__global__ __launch_bounds__(256) void out_gemm_kernel(
    const float* __restrict__ A, const float* __restrict__ Wm,
    const float* __restrict__ bm, float* __restrict__ out)
{
  __shared__ float As[16][68];
  __shared__ float Bs[16][68];
  const int col0 = blockIdx.x * 64;
  const int row0 = blockIdx.y * 64;
  const int tid = threadIdx.x;
  const int tr = tid >> 4, tc = tid & 15;
  float acc[4][4] = {};
  for (int k0 = 0; k0 < 512; k0 += 16) {
    {
      int r = tid >> 2, kk = (tid & 3) << 2;
      float4 a4 = *(const float4*)&A[(size_t)(row0 + r) * 512 + k0 + kk];
      As[kk+0][r] = a4.x; As[kk+1][r] = a4.y; As[kk+2][r] = a4.z; As[kk+3][r] = a4.w;
    }
    {
      int kr = tid >> 4, cc = (tid & 15) << 2;
      *(float4*)&Bs[kr][cc] = *(const float4*)&Wm[(size_t)(k0 + kr) * 1024 + col0 + cc];
    }
    __syncthreads();
    #pragma unroll
    for (int k = 0; k < 16; ++k) {
      float4 av4 = *(const float4*)&As[k][tr*4];
      float4 bv4 = *(const float4*)&Bs[k][tc*4];
      float av[4] = {av4.x, av4.y, av4.z, av4.w};
      float bb[4] = {bv4.x, bv4.y, bv4.z, bv4.w};
      #pragma unroll
      for (int i = 0; i < 4; ++i)
        #pragma unroll
        for (int j = 0; j < 4; ++j)
          acc[i][j] = fmaf(av[i], bb[j], acc[i][j]);
    }
    __syncthreads();
  }
  #pragma unroll
  for (int i = 0; i < 4; ++i) {
    int r = row0 + tr*4 + i;
    #pragma unroll
    for (int j = 0; j < 4; ++j) {
      int c = col0 + tc*4 + j;
      out[(size_t)r * 1024 + c] = acc[i][j] + bm[c];
    }
  }
}

extern "C" void kernel_launch(void* const* d_in, const int* in_sizes, int n_in,
                              void* d_out, int out_size, void* d_ws, size_t ws_size,
                              hipStream_t stream)
{
  const float* x    = (const float*)d_in[0];
  const float* mem  = (const float*)d_in[1];
  const float* addr = (const float*)d_in[2];
  const float* Wk   = (const float*)d_in[3];
  const float* bk   = (const float*)d_in[4];
  const float* Wv   = (const float*)d_in[5];
  const float* bv   = (const float*)d_in[6];
  const float* Wq   = (const float*)d_in[7];
  const float* bq   = (const float*)d_in[8];
  const float* Wm   = (const float*)d_in[9];
  const float* bm   = (const float*)d_in[10];
  float* out  = (float*)d_out;
  float* ws   = (float*)d_ws;
  float* proj = ws;                                   // 1,048,576 floats
  float* attn = proj + (size_t)512 * 2048;            //   262,144 floats
  uint32_t* qaF = (uint32_t*)(attn + (size_t)512 * 512);  // 131,072 u32
  float* m2part = (float*)(qaF + 131072);             // 4,194,304 floats
  float* n2part = m2part + (size_t)1024 * 4096;       //    65,536 floats

  hipLaunchKernelGGL(qa_pack_kernel, dim3(64), dim3(64), 0, stream,
                     addr, qaF);
  hipLaunchKernelGGL(proj_gemm_kernel, dim3(32, 8), dim3(256), 0, stream,
                     x, Wk, bk, Wv, bv, Wq, bq, proj);
  hipLaunchKernelGGL(fused_mem_kernel, dim3(1024), dim3(256), 0, stream,
                     mem, addr, proj, qaF, m2part, n2part);
  hipLaunchKernelGGL(attn_epilogue_kernel, dim3(512), dim3(256), 0, stream,
                     m2part, n2part, proj, attn);
  hipLaunchKernelGGL(out_gemm_kernel, dim3(16, 8), dim3(256), 0, stream,
                     attn, Wm, bm, out);
}

// Round 14
// 170.109 us; speedup vs baseline: 1.2830x; 1.2830x over previous
//
#include <hip/hip_runtime.h>
#include <hip/hip_bf16.h>
#include <math.h>

#define EPSF 1e-5f
#define SELHI 0x05040100u
#define SELLO 0x07060302u

typedef __attribute__((ext_vector_type(8))) short bf16x8;
typedef __attribute__((ext_vector_type(16))) float f32x16;

// pack float -> u32 { low16 = hi-bf16 (truncated), high16 = lo-bf16 (residual) }
__device__ __forceinline__ uint32_t packsplit(float x) {
  uint32_t xb = __builtin_bit_cast(uint32_t, x);
  float hi = __builtin_bit_cast(float, xb & 0xFFFF0000u);
  float resid = x - hi;
  return __builtin_amdgcn_perm(__builtin_bit_cast(uint32_t, resid), xb, 0x07060302u);
}

// float -> bf16 round-to-nearest-even (16-bit value in low bits)
__device__ __forceinline__ uint32_t bf16rne(float x) {
  uint32_t xb = __builtin_bit_cast(uint32_t, x);
  return (xb + 0x7FFFu + ((xb >> 16) & 1u)) >> 16;
}

__device__ __forceinline__ uint4 mkfrag8(const uint32_t* p, uint32_t sel) {
  uint4 u;
  u.x = __builtin_amdgcn_perm(p[1], p[0], sel);
  u.y = __builtin_amdgcn_perm(p[3], p[2], sel);
  u.z = __builtin_amdgcn_perm(p[5], p[4], sel);
  u.w = __builtin_amdgcn_perm(p[7], p[6], sel);
  return u;
}

__device__ __forceinline__ f32x16 mf(uint4 a, uint4 b, f32x16 c) {
  return __builtin_amdgcn_mfma_f32_32x32x16_bf16(
      __builtin_bit_cast(bf16x8, a), __builtin_bit_cast(bf16x8, b), c, 0, 0, 0);
}

#define F4C(v, i) ((i) == 0 ? (v).x : (i) == 1 ? (v).y : (i) == 2 ? (v).z : (v).w)

// =====================================================================
// Kernel 0a: qa fragment precompute (batch-independent, 512 KB, once).
// =====================================================================
__global__ __launch_bounds__(64) void qa_pack_kernel(
    const float* __restrict__ addresses, uint32_t* __restrict__ qaF)
{
  const int T = blockIdx.x;
  const int lane = threadIdx.x;
  const int g32 = lane >> 5, c32 = lane & 31;
  #pragma unroll
  for (int ks = 0; ks < 4; ++ks) {
    const float* ap = addresses + (size_t)(T*32 + c32)*64 + ks*16 + g32*8;
    float4 f0 = *(const float4*)ap;
    float4 f1 = *(const float4*)(ap + 4);
    uint32_t qp[8] = {
      packsplit(fmaxf(f0.x,0.f)), packsplit(fmaxf(f0.y,0.f)),
      packsplit(fmaxf(f0.z,0.f)), packsplit(fmaxf(f0.w,0.f)),
      packsplit(fmaxf(f1.x,0.f)), packsplit(fmaxf(f1.y,0.f)),
      packsplit(fmaxf(f1.z,0.f)), packsplit(fmaxf(f1.w,0.f)) };
    *(uint4*)&qaF[(size_t)T*2048 + (ks*2+0)*256 + lane*4] = mkfrag8(qp, SELHI);
    *(uint4*)&qaF[(size_t)T*2048 + (ks*2+1)*256 + lane*4] = mkfrag8(qp, SELLO);
  }
}

// =====================================================================
// Kernel 0b: W fragment precompute. B-operand layout identical to qaF
//   (validated): lane c32 = output col, k = kstep*16 + g32*8 + j.
//   wFrag[((kstep*2+sel)*64 + ct)*256 + lane*4], 8 MB.
// =====================================================================
__global__ __launch_bounds__(64) void w_pack_kernel(
    const float* __restrict__ Wk, const float* __restrict__ Wv,
    const float* __restrict__ Wq, uint32_t* __restrict__ wFrag)
{
  const int kstep = blockIdx.x;      // 0..63
  const int ct    = blockIdx.y;      // 0..63
  const int lane = threadIdx.x;
  const int g32 = lane >> 5, c32 = lane & 31;
  const int col = ct*32 + c32;
  const float* Wp; int ldb, nc;
  if (col < 512)       { Wp = Wk; ldb = 512;  nc = col; }
  else if (col < 1536) { Wp = Wv; ldb = 1024; nc = col - 512; }
  else                 { Wp = Wq; ldb = 512;  nc = col - 1536; }
  uint32_t p[8];
  #pragma unroll
  for (int j = 0; j < 8; ++j)
    p[j] = packsplit(Wp[(size_t)(kstep*16 + g32*8 + j) * ldb + nc]);
  *(uint4*)&wFrag[((size_t)(kstep*2+0)*64 + ct)*256 + lane*4] = mkfrag8(p, SELHI);
  *(uint4*)&wFrag[((size_t)(kstep*2+1)*64 + ct)*256 + lane*4] = mkfrag8(p, SELLO);
}

// =====================================================================
// Kernel 0c: x fragment precompute. A-operand layout identical to
//   fkFrag (validated): lane c32 = output row, k = kstep*16 + g32*8 + j.
//   xFrag[((kstep*2+sel)*16 + rt)*256 + lane*4], 2 MB.
// =====================================================================
__global__ __launch_bounds__(64) void x_pack_kernel(
    const float* __restrict__ x, uint32_t* __restrict__ xFrag)
{
  const int kstep = blockIdx.x;      // 0..63
  const int rt    = blockIdx.y;      // 0..15
  const int lane = threadIdx.x;
  const int g32 = lane >> 5, c32 = lane & 31;
  const float* xp = x + (size_t)(rt*32 + c32)*1024 + kstep*16 + g32*8;
  float4 f0 = *(const float4*)xp;
  float4 f1 = *(const float4*)(xp + 4);
  uint32_t p[8] = { packsplit(f0.x), packsplit(f0.y), packsplit(f0.z), packsplit(f0.w),
                    packsplit(f1.x), packsplit(f1.y), packsplit(f1.z), packsplit(f1.w) };
  *(uint4*)&xFrag[((size_t)(kstep*2+0)*16 + rt)*256 + lane*4] = mkfrag8(p, SELHI);
  *(uint4*)&xFrag[((size_t)(kstep*2+1)*16 + rt)*256 + lane*4] = mkfrag8(p, SELLO);
}

// =====================================================================
// Kernel 1: proj via MFMA (split-3 bf16). Grid 256 x 256 threads;
//   wave w of block bx owns output tile (rt, ct):
//   rt = (bx>>5)*2 + (w>>1), ct = (bx&31)*2 + (w&1).
//   No LDS: fragments stream from the L2-resident tables.
//   Epilogue: +bias, relu for k/q segments, validated C-layout store.
// =====================================================================
__global__ __launch_bounds__(256) void proj_mfma_kernel(
    const uint32_t* __restrict__ xFrag, const uint32_t* __restrict__ wFrag,
    const float* __restrict__ bk, const float* __restrict__ bv,
    const float* __restrict__ bq, float* __restrict__ proj)
{
  const int tid = threadIdx.x;
  const int wave = tid >> 6, lane = tid & 63;
  const int g32 = lane >> 5, c32 = lane & 31;
  const int rt = ((blockIdx.x >> 5) << 1) + (wave >> 1);
  const int ct = ((blockIdx.x & 31) << 1) + (wave & 1);

  f32x16 acc;
  #pragma unroll
  for (int r = 0; r < 16; ++r) acc[r] = 0.f;

  const uint32_t* xb = xFrag + (size_t)rt*256 + lane*4;
  const uint32_t* wb = wFrag + (size_t)ct*256 + lane*4;

  #pragma unroll 2
  for (int ks = 0; ks < 64; ++ks) {
    uint4 Ah = *(const uint4*)(xb + (size_t)(ks*2+0)*16*256);
    uint4 Al = *(const uint4*)(xb + (size_t)(ks*2+1)*16*256);
    uint4 Bh = *(const uint4*)(wb + (size_t)(ks*2+0)*64*256);
    uint4 Bl = *(const uint4*)(wb + (size_t)(ks*2+1)*64*256);
    acc = mf(Ah, Bh, acc);
    acc = mf(Ah, Bl, acc);
    acc = mf(Al, Bh, acc);
  }

  const int col = ct*32 + c32;
  const float* bias; int nc, relu;
  if (col < 512)       { bias = bk; nc = col;        relu = 1; }
  else if (col < 1536) { bias = bv; nc = col - 512;  relu = 0; }
  else                 { bias = bq; nc = col - 1536; relu = 1; }
  const float bvv = bias[nc];
  #pragma unroll
  for (int r = 0; r < 16; ++r) {
    const int m = rt*32 + (r & 3) + 8*(r >> 2) + 4*g32;
    float v = acc[r] + bvv;
    if (relu) v = fmaxf(v, 0.f);
    proj[(size_t)m * 2048 + col] = v;
  }
}

// =====================================================================
// Kernel 2: fused memory kernel (R11 exact — best known, no spill).
// =====================================================================
__global__ __launch_bounds__(256, 2) void fused_mem_kernel(
    const float* __restrict__ memories,   // [512][2048][64]
    const float* __restrict__ addresses,  // [2048][64]
    const float* __restrict__ proj,       // [512][2048] = fk|v|fq
    const uint32_t* __restrict__ qaF,     // [64][8][64][4] qa fragments
    float* __restrict__ attn)             // [512][512]
{
  __shared__ uint32_t SH[12800];

  const int b = blockIdx.x, tid = threadIdx.x;
  const int wave = tid >> 6, lane = tid & 63;
  const int g32 = lane >> 5, c32 = lane & 31;

  uint32_t* fkFrag = SH;
  uint32_t* vFrag  = SH + 2048;
  uint32_t* pkbase = SH + 4096;
  unsigned short* pF16 = (unsigned short*)(pkbase + wave * 2176);  // [32][68]
  unsigned short* pN16 = pF16 + 2176;

  float* pbuf = (float*)pkbase;
  {
    const float* prow = proj + (size_t)b * 2048;
    *(float4*)&pbuf[tid*8]   = *(const float4*)&prow[tid*8];
    *(float4*)&pbuf[tid*8+4] = *(const float4*)&prow[tid*8+4];
  }
  __syncthreads();

  {
    const int ks = wave;
    float4 f0 = *(const float4*)&pbuf[c32*64 + ks*16 + g32*8];
    float4 f1 = *(const float4*)&pbuf[c32*64 + ks*16 + g32*8 + 4];
    uint32_t p[8] = { packsplit(f0.x), packsplit(f0.y), packsplit(f0.z), packsplit(f0.w),
                      packsplit(f1.x), packsplit(f1.y), packsplit(f1.z), packsplit(f1.w) };
    *(uint4*)&fkFrag[((ks*2+0)*64 + lane)*4] = mkfrag8(p, SELHI);
    *(uint4*)&fkFrag[((ks*2+1)*64 + lane)*4] = mkfrag8(p, SELLO);
    const int t = wave;
    uint32_t q[8];
    #pragma unroll
    for (int j = 0; j < 8; ++j) {
      int h = (g32*8 + j) & 7;
      q[j] = packsplit(pbuf[512 + h*128 + t*32 + c32]);
    }
    *(uint4*)&vFrag[((t*2+0)*64 + lane)*4] = mkfrag8(q, SELHI);
    *(uint4*)&vFrag[((t*2+1)*64 + lane)*4] = mkfrag8(q, SELLO);
  }
  __syncthreads();

  f32x16 Zv;
  #pragma unroll
  for (int r = 0; r < 16; ++r) Zv[r] = 0.f;
  f32x16 aD00 = Zv, aD01 = Zv, aD10 = Zv, aD11 = Zv;
  float n2a[32];
  #pragma unroll
  for (int k = 0; k < 32; ++k) n2a[k] = 0.f;

  const float* aRow0 = addresses + (size_t)(wave*512 + c32) * 64;
  const float* mRow0 = memories + ((size_t)b*2048 + wave*512 + c32) * 64;
  const uint32_t* qaBase = qaF + (size_t)(wave*16)*2048 + lane*4;

  auto do_mfma = [&](int base) {
    uint32_t f0[4], f1[4], n0[4], n1[4];
    #pragma unroll
    for (int e = 0; e < 4; ++e) {
      const int r0 = (base + g32*8 + 2*e) * 68;
      const int r1 = r0 + 68;
      f0[e] = (uint32_t)pF16[r0 + c32]      | ((uint32_t)pF16[r1 + c32] << 16);
      f1[e] = (uint32_t)pF16[r0 + 32 + c32] | ((uint32_t)pF16[r1 + 32 + c32] << 16);
      n0[e] = (uint32_t)pN16[r0 + c32]      | ((uint32_t)pN16[r1 + c32] << 16);
      n1[e] = (uint32_t)pN16[r0 + 32 + c32] | ((uint32_t)pN16[r1 + 32 + c32] << 16);
    }
    uint4 A0 = make_uint4(f0[0], f0[1], f0[2], f0[3]);
    uint4 A1 = make_uint4(f1[0], f1[1], f1[2], f1[3]);
    uint4 B0 = make_uint4(n0[0], n0[1], n0[2], n0[3]);
    uint4 B1 = make_uint4(n1[0], n1[1], n1[2], n1[3]);
    aD00 = mf(A0, B0, aD00);
    aD01 = mf(A0, B1, aD01);
    aD10 = mf(A1, B0, aD10);
    aD11 = mf(A1, B1, aD11);
  };

#define QATAB_B(QP, ACC) do {                                          \
    _Pragma("unroll")                                                  \
    for (int ks = 0; ks < 4; ++ks) {                                   \
      uint4 qh_ = *(const uint4*)((QP) + (ks*2+0)*256);                \
      uint4 ql_ = *(const uint4*)((QP) + (ks*2+1)*256);                \
      uint4 Ah_ = *(uint4*)&fkFrag[((ks*2+0)*64 + lane)*4];            \
      uint4 Al_ = *(uint4*)&fkFrag[((ks*2+1)*64 + lane)*4];            \
      ACC = mf(Ah_, qh_, ACC); ACC = mf(Ah_, ql_, ACC); ACC = mf(Al_, qh_, ACC); \
    } } while(0)

#define ELEM(T2, ACU, ACW) do {                                        \
    unsigned short* rowF_ = pF16 + c32*68;                             \
    unsigned short* rowN_ = pN16 + c32*68;                             \
    _Pragma("unroll")                                                  \
    for (int rq = 0; rq < 4; ++rq) {                                   \
      uint32_t pf_[4], pn_[4];                                         \
      _Pragma("unroll")                                                \
      for (int i = 0; i < 4; ++i) {                                    \
        const int r = rq*4 + i;                                        \
        float upd = ACU[r];                                            \
        float wx  = ACW[r];                                            \
        float wp  = __builtin_amdgcn_rcpf(1.f + __expf(-wx));          \
        float mv  = F4C(M_[(T2)*4 + rq], i);                           \
        float av  = F4C(E_[rq & 1], i);                                \
        float nm  = fmaf(wp, upd - mv, mv);                            \
        float fv  = fmaxf(nm + av, 0.f);                               \
        n2a[(T2)*16 + r] += fv;                                        \
        pn_[i] = bf16rne(nm);                                          \
        pf_[i] = bf16rne(fv);                                          \
      }                                                                \
      if (rq == 1) { E_[0] = *(const float4*)(ap0 + (T2)*32 + 16 + g32*4);      \
                     E_[1] = *(const float4*)(ap0 + (T2)*32 + 16 + g32*4 + 8); }\
      const int col = 32*(T2) + 8*rq + 4*g32;                          \
      *(uint2*)&rowF_[col] = make_uint2(pf_[0] | (pf_[1]<<16), pf_[2] | (pf_[3]<<16)); \
      *(uint2*)&rowN_[col] = make_uint2(pn_[0] | (pn_[1]<<16), pn_[2] | (pn_[3]<<16)); \
    } } while(0)

  f32x16 aBcur = Zv, aBnext;
  float4 M_[8];
  QATAB_B(qaBase, aBcur);
  #pragma unroll
  for (int k = 0; k < 8; ++k) M_[k] = *(const float4*)(mRow0 + k*8 + g32*4);

  #pragma unroll 1
  for (int ss = 0; ss < 16; ++ss) {
    asm volatile("" ::: "memory");

    float s0 = aBcur[0], s1 = aBcur[1], s2 = aBcur[2], s3 = aBcur[3];
    float own = (s0 + s1) + (s2 + s3);
    float den = own + __shfl_xor(own, 32) + EPSF;
    float rden = __builtin_amdgcn_rcpf(den);
    float p0 = __shfl_xor(s0, 32), p1 = __shfl_xor(s1, 32),
          p2 = __shfl_xor(s2, 32), p3 = __shfl_xor(s3, 32);
    float rm = (g32 == 0) ? rden : 0.f;
    uint32_t sp[8] = { packsplit(s0*rm), packsplit(s1*rm), packsplit(s2*rm), packsplit(s3*rm),
                       packsplit(p0*rm), packsplit(p1*rm), packsplit(p2*rm), packsplit(p3*rm) };
    uint4 Sh = mkfrag8(sp, SELHI), Sl = mkfrag8(sp, SELLO);

    f32x16 aC0 = Zv, aC2 = Zv;
    {
      uint4 Vh, Vl;
      Vh = *(uint4*)&vFrag[(0*64 + lane)*4]; Vl = *(uint4*)&vFrag[(1*64 + lane)*4];
      aC0 = mf(Vh, Sh, aC0); aC0 = mf(Vh, Sl, aC0); aC0 = mf(Vl, Sh, aC0);
      Vh = *(uint4*)&vFrag[(4*64 + lane)*4]; Vl = *(uint4*)&vFrag[(5*64 + lane)*4];
      aC2 = mf(Vh, Sh, aC2); aC2 = mf(Vh, Sl, aC2); aC2 = mf(Vl, Sh, aC2);
    }

    aBnext = Zv;
    if (ss < 15) {
      const uint32_t* qp = qaBase + (size_t)(ss+1)*2048;
      QATAB_B(qp, aBnext);
    }

    const float* ap0 = aRow0 + (size_t)ss * 2048;
    float4 E_[2];
    E_[0] = *(const float4*)(ap0 + g32*4);
    E_[1] = *(const float4*)(ap0 + g32*4 + 8);
    ELEM(0, aC0, aC2);

    f32x16 aC1 = Zv, aC3 = Zv;
    {
      uint4 Vh, Vl;
      Vh = *(uint4*)&vFrag[(2*64 + lane)*4]; Vl = *(uint4*)&vFrag[(3*64 + lane)*4];
      aC1 = mf(Vh, Sh, aC1); aC1 = mf(Vh, Sl, aC1); aC1 = mf(Vl, Sh, aC1);
      Vh = *(uint4*)&vFrag[(6*64 + lane)*4]; Vl = *(uint4*)&vFrag[(7*64 + lane)*4];
      aC3 = mf(Vh, Sh, aC3); aC3 = mf(Vh, Sl, aC3); aC3 = mf(Vl, Sh, aC3);
    }

    if (ss < 15) {
      const float* mp = mRow0 + (size_t)(ss+1) * 2048;
      #pragma unroll
      for (int k = 0; k < 4; ++k) M_[k] = *(const float4*)(mp + k*8 + g32*4);
    }

    E_[0] = *(const float4*)(ap0 + 32 + g32*4);
    E_[1] = *(const float4*)(ap0 + 32 + g32*4 + 8);
    ELEM(1, aC1, aC3);

    if (ss < 15) {
      const float* mp = mRow0 + (size_t)(ss+1) * 2048;
      #pragma unroll
      for (int k = 4; k < 8; ++k) M_[k] = *(const float4*)(mp + k*8 + g32*4);
    }

    asm volatile("" ::: "memory");
    do_mfma(0);
    do_mfma(16);

    aBcur = aBnext;
  }

  // ================= epilogue =================
  __syncthreads();

  float* n2stageF = (float*)SH;            // [4][64]
  float* norm2F   = ((float*)SH) + 256;    // [64]
  float* den2F    = ((float*)SH) + 320;    // [8]
  float* stageF   = (float*)pkbase;        // [4][16][66]
  const float* fqg = proj + (size_t)b * 2048 + 1536;

  #pragma unroll
  for (int k = 0; k < 32; ++k) {
    float v = n2a[k];
    v += __shfl_xor(v, 1); v += __shfl_xor(v, 2); v += __shfl_xor(v, 4);
    v += __shfl_xor(v, 8); v += __shfl_xor(v, 16);
    n2a[k] = v;
  }
  if (c32 == 0) {
    #pragma unroll
    for (int t2 = 0; t2 < 2; ++t2)
      #pragma unroll
      for (int r = 0; r < 16; ++r) {
        const int j = 32*t2 + 8*(r>>2) + (r&3) + 4*g32;
        n2stageF[wave*64 + j] = n2a[t2*16 + r];
      }
  }
  __syncthreads();
  if (tid < 64)
    norm2F[tid] = (n2stageF[tid] + n2stageF[64+tid]) + (n2stageF[128+tid] + n2stageF[192+tid]);
  __syncthreads();
  if (tid < 8) {
    float s = 0.f;
    for (int d = 0; d < 64; ++d) s = fmaf(fqg[tid*64 + d], norm2F[d], s);
    den2F[tid] = s + EPSF;
  }

  const int hh = tid >> 5;
  const int ee = (tid & 31) * 2;
  float num2a = 0.f, num2b = 0.f;
  #pragma unroll
  for (int p = 0; p < 4; ++p) {
    const int ti = p >> 1, rh = p & 1;
    #pragma unroll
    for (int q = 0; q < 8; ++q) {
      const int rr = (q & 3) + 8*((q >> 2) & 1) + 4*g32;
      const int r = rh*8 + q;
      float v0 = (ti == 0) ? aD00[r] : aD10[r];
      float v1 = (ti == 0) ? aD01[r] : aD11[r];
      stageF[wave*1056 + rr*66 + c32]      = v0;
      stageF[wave*1056 + rr*66 + 32 + c32] = v1;
    }
    __syncthreads();
    #pragma unroll 8
    for (int dl = 0; dl < 16; ++dl) {
      float2 q0 = *(const float2*)&stageF[0*1056 + dl*66 + ee];
      float2 q1 = *(const float2*)&stageF[1*1056 + dl*66 + ee];
      float2 q2 = *(const float2*)&stageF[2*1056 + dl*66 + ee];
      float2 q3 = *(const float2*)&stageF[3*1056 + dl*66 + ee];
      float v0 = (q0.x + q1.x) + (q2.x + q3.x);
      float v1 = (q0.y + q1.y) + (q2.y + q3.y);
      float fv = fqg[hh*64 + p*16 + dl];
      num2a = fmaf(fv, v0, num2a);
      num2b = fmaf(fv, v1, num2b);
    }
    __syncthreads();
  }
  float rd2 = __builtin_amdgcn_rcpf(den2F[hh]);
  attn[(size_t)b*512 + hh*64 + ee]     = num2a * rd2;
  attn[(size_t)b*512 + hh*64 + ee + 1] = num2b * rd2;
#undef ELEM
#undef QATAB_B
}

// =====================================================================
// Kernel 3: out = attn(512x512) @ Wm(512x1024) + bm (unchanged)
// =====================================================================
__global__ __launch_bounds__(256) void out_gemm_kernel(
    const float* __restrict__ A, const float* __restrict__ Wm,
    const float* __restrict__ bm, float* __restrict__ out)
{
  __shared__ float As[16][68];
  __shared__ float Bs[16][68];
  const int col0 = blockIdx.x * 64;
  const int row0 = blockIdx.y * 64;
  const int tid = threadIdx.x;
  const int tr = tid >> 4, tc = tid & 15;
  float acc[4][4] = {};
  for (int k0 = 0; k0 < 512; k0 += 16) {
    {
      int r = tid >> 2, kk = (tid & 3) << 2;
      float4 a4 = *(const float4*)&A[(size_t)(row0 + r) * 512 + k0 + kk];
      As[kk+0][r] = a4.x; As[kk+1][r] = a4.y; As[kk+2][r] = a4.z; As[kk+3][r] = a4.w;
    }
    {
      int kr = tid >> 4, cc = (tid & 15) << 2;
      *(float4*)&Bs[kr][cc] = *(const float4*)&Wm[(size_t)(k0 + kr) * 1024 + col0 + cc];
    }
    __syncthreads();
    #pragma unroll
    for (int k = 0; k < 16; ++k) {
      float4 av4 = *(const float4*)&As[k][tr*4];
      float4 bv4 = *(const float4*)&Bs[k][tc*4];
      float av[4] = {av4.x, av4.y, av4.z, av4.w};
      float bb[4] = {bv4.x, bv4.y, bv4.z, bv4.w};
      #pragma unroll
      for (int i = 0; i < 4; ++i)
        #pragma unroll
        for (int j = 0; j < 4; ++j)
          acc[i][j] = fmaf(av[i], bb[j], acc[i][j]);
    }
    __syncthreads();
  }
  #pragma unroll
  for (int i = 0; i < 4; ++i) {
    int r = row0 + tr*4 + i;
    #pragma unroll
    for (int j = 0; j < 4; ++j) {
      int c = col0 + tc*4 + j;
      out[(size_t)r * 1024 + c] = acc[i][j] + bm[c];
    }
  }
}

extern "C" void kernel_launch(void* const* d_in, const int* in_sizes, int n_in,
                              void* d_out, int out_size, void* d_ws, size_t ws_size,
                              hipStream_t stream)
{
  const float* x    = (const float*)d_in[0];
  const float* mem  = (const float*)d_in[1];
  const float* addr = (const float*)d_in[2];
  const float* Wk   = (const float*)d_in[3];
  const float* bk   = (const float*)d_in[4];
  const float* Wv   = (const float*)d_in[5];
  const float* bv   = (const float*)d_in[6];
  const float* Wq   = (const float*)d_in[7];
  const float* bq   = (const float*)d_in[8];
  const float* Wm   = (const float*)d_in[9];
  const float* bm   = (const float*)d_in[10];
  float* out  = (float*)d_out;
  float* ws   = (float*)d_ws;
  float* proj = ws;                                       // 1,048,576 f (4 MB)
  float* attn = proj + (size_t)512 * 2048;                //   262,144 f (1 MB)
  uint32_t* qaF   = (uint32_t*)(attn + (size_t)512*512);  //   131,072 u32 (0.5 MB)
  uint32_t* wFrag = qaF + 131072;                         // 2,097,152 u32 (8 MB)
  uint32_t* xFrag = wFrag + 2097152;                      //   524,288 u32 (2 MB)

  hipLaunchKernelGGL(qa_pack_kernel, dim3(64), dim3(64), 0, stream,
                     addr, qaF);
  hipLaunchKernelGGL(w_pack_kernel, dim3(64, 64), dim3(64), 0, stream,
                     Wk, Wv, Wq, wFrag);
  hipLaunchKernelGGL(x_pack_kernel, dim3(64, 16), dim3(64), 0, stream,
                     x, xFrag);
  hipLaunchKernelGGL(proj_mfma_kernel, dim3(256), dim3(256), 0, stream,
                     xFrag, wFrag, bk, bv, bq, proj);
  hipLaunchKernelGGL(fused_mem_kernel, dim3(512), dim3(256), 0, stream,
                     mem, addr, proj, qaF, attn);
  hipLaunchKernelGGL(out_gemm_kernel, dim3(16, 8), dim3(256), 0, stream,
                     attn, Wm, bm, out);
}

// Round 15
// 128.979 us; speedup vs baseline: 1.6922x; 1.3189x over previous
//
#include <hip/hip_runtime.h>
#include <hip/hip_bf16.h>
#include <math.h>

#define EPSF 1e-5f
#define SELHI 0x05040100u
#define SELLO 0x07060302u

typedef __attribute__((ext_vector_type(8))) short bf16x8;
typedef __attribute__((ext_vector_type(16))) float f32x16;

// pack float -> u32 { low16 = hi-bf16 (truncated), high16 = lo-bf16 (residual) }
__device__ __forceinline__ uint32_t packsplit(float x) {
  uint32_t xb = __builtin_bit_cast(uint32_t, x);
  float hi = __builtin_bit_cast(float, xb & 0xFFFF0000u);
  float resid = x - hi;
  return __builtin_amdgcn_perm(__builtin_bit_cast(uint32_t, resid), xb, 0x07060302u);
}

// float -> bf16 round-to-nearest-even (16-bit value in low bits)
__device__ __forceinline__ uint32_t bf16rne(float x) {
  uint32_t xb = __builtin_bit_cast(uint32_t, x);
  return (xb + 0x7FFFu + ((xb >> 16) & 1u)) >> 16;
}

__device__ __forceinline__ uint4 mkfrag8(const uint32_t* p, uint32_t sel) {
  uint4 u;
  u.x = __builtin_amdgcn_perm(p[1], p[0], sel);
  u.y = __builtin_amdgcn_perm(p[3], p[2], sel);
  u.z = __builtin_amdgcn_perm(p[5], p[4], sel);
  u.w = __builtin_amdgcn_perm(p[7], p[6], sel);
  return u;
}

__device__ __forceinline__ f32x16 mf(uint4 a, uint4 b, f32x16 c) {
  return __builtin_amdgcn_mfma_f32_32x32x16_bf16(
      __builtin_bit_cast(bf16x8, a), __builtin_bit_cast(bf16x8, b), c, 0, 0, 0);
}

#define F4C(v, i) ((i) == 0 ? (v).x : (i) == 1 ? (v).y : (i) == 2 ? (v).z : (v).w)

// =====================================================================
// Kernel 0: ALL fragment precomputes in ONE dispatch (flat grid 6208).
//   [0,4096)      W (Wk|Wv|Wq) -> wFrag   (8 MB)
//   [4096,5120)   x            -> xFrag   (2 MB)
//   [5120,5184)   addresses    -> qaF     (0.5 MB)
//   [5184,6208)   Wm           -> wmFrag  (2 MB)
// =====================================================================
__global__ __launch_bounds__(64) void pack_all_kernel(
    const float* __restrict__ addresses,
    const float* __restrict__ x,
    const float* __restrict__ Wk, const float* __restrict__ Wv,
    const float* __restrict__ Wq, const float* __restrict__ Wm,
    uint32_t* __restrict__ qaF, uint32_t* __restrict__ xFrag,
    uint32_t* __restrict__ wFrag, uint32_t* __restrict__ wmFrag)
{
  const int bid = blockIdx.x;
  const int lane = threadIdx.x;
  const int g32 = lane >> 5, c32 = lane & 31;

  if (bid < 4096) {                       // ---- W pack
    const int kstep = bid >> 6, ct = bid & 63;
    const int col = ct*32 + c32;
    const float* Wp; int ldb, nc;
    if (col < 512)       { Wp = Wk; ldb = 512;  nc = col; }
    else if (col < 1536) { Wp = Wv; ldb = 1024; nc = col - 512; }
    else                 { Wp = Wq; ldb = 512;  nc = col - 1536; }
    uint32_t p[8];
    #pragma unroll
    for (int j = 0; j < 8; ++j)
      p[j] = packsplit(Wp[(size_t)(kstep*16 + g32*8 + j) * ldb + nc]);
    *(uint4*)&wFrag[((size_t)(kstep*2+0)*64 + ct)*256 + lane*4] = mkfrag8(p, SELHI);
    *(uint4*)&wFrag[((size_t)(kstep*2+1)*64 + ct)*256 + lane*4] = mkfrag8(p, SELLO);
  } else if (bid < 5120) {                // ---- x pack
    const int t = bid - 4096;
    const int kstep = t >> 4, rt = t & 15;
    const float* xp = x + (size_t)(rt*32 + c32)*1024 + kstep*16 + g32*8;
    float4 f0 = *(const float4*)xp;
    float4 f1 = *(const float4*)(xp + 4);
    uint32_t p[8] = { packsplit(f0.x), packsplit(f0.y), packsplit(f0.z), packsplit(f0.w),
                      packsplit(f1.x), packsplit(f1.y), packsplit(f1.z), packsplit(f1.w) };
    *(uint4*)&xFrag[((size_t)(kstep*2+0)*16 + rt)*256 + lane*4] = mkfrag8(p, SELHI);
    *(uint4*)&xFrag[((size_t)(kstep*2+1)*16 + rt)*256 + lane*4] = mkfrag8(p, SELLO);
  } else if (bid < 5184) {                // ---- qa pack
    const int T = bid - 5120;
    #pragma unroll
    for (int ks = 0; ks < 4; ++ks) {
      const float* ap = addresses + (size_t)(T*32 + c32)*64 + ks*16 + g32*8;
      float4 f0 = *(const float4*)ap;
      float4 f1 = *(const float4*)(ap + 4);
      uint32_t qp[8] = {
        packsplit(fmaxf(f0.x,0.f)), packsplit(fmaxf(f0.y,0.f)),
        packsplit(fmaxf(f0.z,0.f)), packsplit(fmaxf(f0.w,0.f)),
        packsplit(fmaxf(f1.x,0.f)), packsplit(fmaxf(f1.y,0.f)),
        packsplit(fmaxf(f1.z,0.f)), packsplit(fmaxf(f1.w,0.f)) };
      *(uint4*)&qaF[(size_t)T*2048 + (ks*2+0)*256 + lane*4] = mkfrag8(qp, SELHI);
      *(uint4*)&qaF[(size_t)T*2048 + (ks*2+1)*256 + lane*4] = mkfrag8(qp, SELLO);
    }
  } else {                                // ---- Wm pack
    const int t = bid - 5184;
    const int ks = t >> 5, ct = t & 31;
    const int col = ct*32 + c32;
    uint32_t p[8];
    #pragma unroll
    for (int j = 0; j < 8; ++j)
      p[j] = packsplit(Wm[(size_t)(ks*16 + g32*8 + j) * 1024 + col]);
    *(uint4*)&wmFrag[((size_t)(ks*2+0)*32 + ct)*256 + lane*4] = mkfrag8(p, SELHI);
    *(uint4*)&wmFrag[((size_t)(ks*2+1)*32 + ct)*256 + lane*4] = mkfrag8(p, SELLO);
  }
}

// =====================================================================
// Kernel 1: proj via MFMA, K-split x2 for occupancy (2048 waves).
//   Block = 4 waves = 2 tiles x 2 K-halves; LDS combine.
// =====================================================================
__global__ __launch_bounds__(256) void proj_mfma_kernel(
    const uint32_t* __restrict__ xFrag, const uint32_t* __restrict__ wFrag,
    const float* __restrict__ bk, const float* __restrict__ bv,
    const float* __restrict__ bq, float* __restrict__ proj)
{
  __shared__ float red[2][64][16];
  const int tid = threadIdx.x;
  const int wave = tid >> 6, lane = tid & 63;
  const int g32 = lane >> 5, c32 = lane & 31;
  const int tile = blockIdx.x*2 + (wave & 1);
  const int khalf = wave >> 1;
  const int rt = tile >> 6, ct = tile & 63;

  f32x16 acc;
  #pragma unroll
  for (int r = 0; r < 16; ++r) acc[r] = 0.f;

  const uint32_t* xb = xFrag + (size_t)rt*256 + lane*4;
  const uint32_t* wb = wFrag + (size_t)ct*256 + lane*4;

  #pragma unroll 2
  for (int k8 = 0; k8 < 32; ++k8) {
    const int ks = khalf*32 + k8;
    uint4 Ah = *(const uint4*)(xb + (size_t)(ks*2+0)*16*256);
    uint4 Al = *(const uint4*)(xb + (size_t)(ks*2+1)*16*256);
    uint4 Bh = *(const uint4*)(wb + (size_t)(ks*2+0)*64*256);
    uint4 Bl = *(const uint4*)(wb + (size_t)(ks*2+1)*64*256);
    acc = mf(Ah, Bh, acc);
    acc = mf(Ah, Bl, acc);
    acc = mf(Al, Bh, acc);
  }

  if (khalf == 1) {
    #pragma unroll
    for (int r = 0; r < 16; ++r) red[wave & 1][lane][r] = acc[r];
  }
  __syncthreads();
  if (khalf == 0) {
    const int col = ct*32 + c32;
    const float* bias; int nc, relu;
    if (col < 512)       { bias = bk; nc = col;        relu = 1; }
    else if (col < 1536) { bias = bv; nc = col - 512;  relu = 0; }
    else                 { bias = bq; nc = col - 1536; relu = 1; }
    const float bvv = bias[nc];
    #pragma unroll
    for (int r = 0; r < 16; ++r) {
      const int m = rt*32 + (r & 3) + 8*(r >> 2) + 4*g32;
      float v = acc[r] + red[wave & 1][lane][r] + bvv;
      if (relu) v = fmaxf(v, 0.f);
      proj[(size_t)m * 2048 + col] = v;
    }
  }
}

// =====================================================================
// Kernel 2: fused memory kernel (R11 body; epilogue now stores attn as
//   split-bf16 hi/lo u16 planes — free pack from registers, feeds
//   out_mfma's A-operand directly).
// =====================================================================
__global__ __launch_bounds__(256, 2) void fused_mem_kernel(
    const float* __restrict__ memories,   // [512][2048][64]
    const float* __restrict__ addresses,  // [2048][64]
    const float* __restrict__ proj,       // [512][2048] = fk|v|fq
    const uint32_t* __restrict__ qaF,     // [64][8][64][4] qa fragments
    uint32_t* __restrict__ attnHi,        // [512][256] u32 (2 cols each)
    uint32_t* __restrict__ attnLo)        // [512][256]
{
  __shared__ uint32_t SH[12800];

  const int b = blockIdx.x, tid = threadIdx.x;
  const int wave = tid >> 6, lane = tid & 63;
  const int g32 = lane >> 5, c32 = lane & 31;

  uint32_t* fkFrag = SH;
  uint32_t* vFrag  = SH + 2048;
  uint32_t* pkbase = SH + 4096;
  unsigned short* pF16 = (unsigned short*)(pkbase + wave * 2176);  // [32][68]
  unsigned short* pN16 = pF16 + 2176;

  float* pbuf = (float*)pkbase;
  {
    const float* prow = proj + (size_t)b * 2048;
    *(float4*)&pbuf[tid*8]   = *(const float4*)&prow[tid*8];
    *(float4*)&pbuf[tid*8+4] = *(const float4*)&prow[tid*8+4];
  }
  __syncthreads();

  {
    const int ks = wave;
    float4 f0 = *(const float4*)&pbuf[c32*64 + ks*16 + g32*8];
    float4 f1 = *(const float4*)&pbuf[c32*64 + ks*16 + g32*8 + 4];
    uint32_t p[8] = { packsplit(f0.x), packsplit(f0.y), packsplit(f0.z), packsplit(f0.w),
                      packsplit(f1.x), packsplit(f1.y), packsplit(f1.z), packsplit(f1.w) };
    *(uint4*)&fkFrag[((ks*2+0)*64 + lane)*4] = mkfrag8(p, SELHI);
    *(uint4*)&fkFrag[((ks*2+1)*64 + lane)*4] = mkfrag8(p, SELLO);
    const int t = wave;
    uint32_t q[8];
    #pragma unroll
    for (int j = 0; j < 8; ++j) {
      int h = (g32*8 + j) & 7;
      q[j] = packsplit(pbuf[512 + h*128 + t*32 + c32]);
    }
    *(uint4*)&vFrag[((t*2+0)*64 + lane)*4] = mkfrag8(q, SELHI);
    *(uint4*)&vFrag[((t*2+1)*64 + lane)*4] = mkfrag8(q, SELLO);
  }
  __syncthreads();

  f32x16 Zv;
  #pragma unroll
  for (int r = 0; r < 16; ++r) Zv[r] = 0.f;
  f32x16 aD00 = Zv, aD01 = Zv, aD10 = Zv, aD11 = Zv;
  float n2a[32];
  #pragma unroll
  for (int k = 0; k < 32; ++k) n2a[k] = 0.f;

  const float* aRow0 = addresses + (size_t)(wave*512 + c32) * 64;
  const float* mRow0 = memories + ((size_t)b*2048 + wave*512 + c32) * 64;
  const uint32_t* qaBase = qaF + (size_t)(wave*16)*2048 + lane*4;

  auto do_mfma = [&](int base) {
    uint32_t f0[4], f1[4], n0[4], n1[4];
    #pragma unroll
    for (int e = 0; e < 4; ++e) {
      const int r0 = (base + g32*8 + 2*e) * 68;
      const int r1 = r0 + 68;
      f0[e] = (uint32_t)pF16[r0 + c32]      | ((uint32_t)pF16[r1 + c32] << 16);
      f1[e] = (uint32_t)pF16[r0 + 32 + c32] | ((uint32_t)pF16[r1 + 32 + c32] << 16);
      n0[e] = (uint32_t)pN16[r0 + c32]      | ((uint32_t)pN16[r1 + c32] << 16);
      n1[e] = (uint32_t)pN16[r0 + 32 + c32] | ((uint32_t)pN16[r1 + 32 + c32] << 16);
    }
    uint4 A0 = make_uint4(f0[0], f0[1], f0[2], f0[3]);
    uint4 A1 = make_uint4(f1[0], f1[1], f1[2], f1[3]);
    uint4 B0 = make_uint4(n0[0], n0[1], n0[2], n0[3]);
    uint4 B1 = make_uint4(n1[0], n1[1], n1[2], n1[3]);
    aD00 = mf(A0, B0, aD00);
    aD01 = mf(A0, B1, aD01);
    aD10 = mf(A1, B0, aD10);
    aD11 = mf(A1, B1, aD11);
  };

#define QATAB_B(QP, ACC) do {                                          \
    _Pragma("unroll")                                                  \
    for (int ks = 0; ks < 4; ++ks) {                                   \
      uint4 qh_ = *(const uint4*)((QP) + (ks*2+0)*256);                \
      uint4 ql_ = *(const uint4*)((QP) + (ks*2+1)*256);                \
      uint4 Ah_ = *(uint4*)&fkFrag[((ks*2+0)*64 + lane)*4];            \
      uint4 Al_ = *(uint4*)&fkFrag[((ks*2+1)*64 + lane)*4];            \
      ACC = mf(Ah_, qh_, ACC); ACC = mf(Ah_, ql_, ACC); ACC = mf(Al_, qh_, ACC); \
    } } while(0)

#define ELEM(T2, ACU, ACW) do {                                        \
    unsigned short* rowF_ = pF16 + c32*68;                             \
    unsigned short* rowN_ = pN16 + c32*68;                             \
    _Pragma("unroll")                                                  \
    for (int rq = 0; rq < 4; ++rq) {                                   \
      uint32_t pf_[4], pn_[4];                                         \
      _Pragma("unroll")                                                \
      for (int i = 0; i < 4; ++i) {                                    \
        const int r = rq*4 + i;                                        \
        float upd = ACU[r];                                            \
        float wx  = ACW[r];                                            \
        float wp  = __builtin_amdgcn_rcpf(1.f + __expf(-wx));          \
        float mv  = F4C(M_[(T2)*4 + rq], i);                           \
        float av  = F4C(E_[rq & 1], i);                                \
        float nm  = fmaf(wp, upd - mv, mv);                            \
        float fv  = fmaxf(nm + av, 0.f);                               \
        n2a[(T2)*16 + r] += fv;                                        \
        pn_[i] = bf16rne(nm);                                          \
        pf_[i] = bf16rne(fv);                                          \
      }                                                                \
      if (rq == 1) { E_[0] = *(const float4*)(ap0 + (T2)*32 + 16 + g32*4);      \
                     E_[1] = *(const float4*)(ap0 + (T2)*32 + 16 + g32*4 + 8); }\
      const int col = 32*(T2) + 8*rq + 4*g32;                          \
      *(uint2*)&rowF_[col] = make_uint2(pf_[0] | (pf_[1]<<16), pf_[2] | (pf_[3]<<16)); \
      *(uint2*)&rowN_[col] = make_uint2(pn_[0] | (pn_[1]<<16), pn_[2] | (pn_[3]<<16)); \
    } } while(0)

  f32x16 aBcur = Zv, aBnext;
  float4 M_[8];
  QATAB_B(qaBase, aBcur);
  #pragma unroll
  for (int k = 0; k < 8; ++k) M_[k] = *(const float4*)(mRow0 + k*8 + g32*4);

  #pragma unroll 1
  for (int ss = 0; ss < 16; ++ss) {
    asm volatile("" ::: "memory");

    float s0 = aBcur[0], s1 = aBcur[1], s2 = aBcur[2], s3 = aBcur[3];
    float own = (s0 + s1) + (s2 + s3);
    float den = own + __shfl_xor(own, 32) + EPSF;
    float rden = __builtin_amdgcn_rcpf(den);
    float p0 = __shfl_xor(s0, 32), p1 = __shfl_xor(s1, 32),
          p2 = __shfl_xor(s2, 32), p3 = __shfl_xor(s3, 32);
    float rm = (g32 == 0) ? rden : 0.f;
    uint32_t sp[8] = { packsplit(s0*rm), packsplit(s1*rm), packsplit(s2*rm), packsplit(s3*rm),
                       packsplit(p0*rm), packsplit(p1*rm), packsplit(p2*rm), packsplit(p3*rm) };
    uint4 Sh = mkfrag8(sp, SELHI), Sl = mkfrag8(sp, SELLO);

    f32x16 aC0 = Zv, aC2 = Zv;
    {
      uint4 Vh, Vl;
      Vh = *(uint4*)&vFrag[(0*64 + lane)*4]; Vl = *(uint4*)&vFrag[(1*64 + lane)*4];
      aC0 = mf(Vh, Sh, aC0); aC0 = mf(Vh, Sl, aC0); aC0 = mf(Vl, Sh, aC0);
      Vh = *(uint4*)&vFrag[(4*64 + lane)*4]; Vl = *(uint4*)&vFrag[(5*64 + lane)*4];
      aC2 = mf(Vh, Sh, aC2); aC2 = mf(Vh, Sl, aC2); aC2 = mf(Vl, Sh, aC2);
    }

    aBnext = Zv;
    if (ss < 15) {
      const uint32_t* qp = qaBase + (size_t)(ss+1)*2048;
      QATAB_B(qp, aBnext);
    }

    const float* ap0 = aRow0 + (size_t)ss * 2048;
    float4 E_[2];
    E_[0] = *(const float4*)(ap0 + g32*4);
    E_[1] = *(const float4*)(ap0 + g32*4 + 8);
    ELEM(0, aC0, aC2);

    f32x16 aC1 = Zv, aC3 = Zv;
    {
      uint4 Vh, Vl;
      Vh = *(uint4*)&vFrag[(2*64 + lane)*4]; Vl = *(uint4*)&vFrag[(3*64 + lane)*4];
      aC1 = mf(Vh, Sh, aC1); aC1 = mf(Vh, Sl, aC1); aC1 = mf(Vl, Sh, aC1);
      Vh = *(uint4*)&vFrag[(6*64 + lane)*4]; Vl = *(uint4*)&vFrag[(7*64 + lane)*4];
      aC3 = mf(Vh, Sh, aC3); aC3 = mf(Vh, Sl, aC3); aC3 = mf(Vl, Sh, aC3);
    }

    if (ss < 15) {
      const float* mp = mRow0 + (size_t)(ss+1) * 2048;
      #pragma unroll
      for (int k = 0; k < 4; ++k) M_[k] = *(const float4*)(mp + k*8 + g32*4);
    }

    E_[0] = *(const float4*)(ap0 + 32 + g32*4);
    E_[1] = *(const float4*)(ap0 + 32 + g32*4 + 8);
    ELEM(1, aC1, aC3);

    if (ss < 15) {
      const float* mp = mRow0 + (size_t)(ss+1) * 2048;
      #pragma unroll
      for (int k = 4; k < 8; ++k) M_[k] = *(const float4*)(mp + k*8 + g32*4);
    }

    asm volatile("" ::: "memory");
    do_mfma(0);
    do_mfma(16);

    aBcur = aBnext;
  }

  // ================= epilogue =================
  __syncthreads();

  float* n2stageF = (float*)SH;            // [4][64]
  float* norm2F   = ((float*)SH) + 256;    // [64]
  float* den2F    = ((float*)SH) + 320;    // [8]
  float* stageF   = (float*)pkbase;        // [4][16][66]
  const float* fqg = proj + (size_t)b * 2048 + 1536;

  #pragma unroll
  for (int k = 0; k < 32; ++k) {
    float v = n2a[k];
    v += __shfl_xor(v, 1); v += __shfl_xor(v, 2); v += __shfl_xor(v, 4);
    v += __shfl_xor(v, 8); v += __shfl_xor(v, 16);
    n2a[k] = v;
  }
  if (c32 == 0) {
    #pragma unroll
    for (int t2 = 0; t2 < 2; ++t2)
      #pragma unroll
      for (int r = 0; r < 16; ++r) {
        const int j = 32*t2 + 8*(r>>2) + (r&3) + 4*g32;
        n2stageF[wave*64 + j] = n2a[t2*16 + r];
      }
  }
  __syncthreads();
  if (tid < 64)
    norm2F[tid] = (n2stageF[tid] + n2stageF[64+tid]) + (n2stageF[128+tid] + n2stageF[192+tid]);
  __syncthreads();
  if (tid < 8) {
    float s = 0.f;
    for (int d = 0; d < 64; ++d) s = fmaf(fqg[tid*64 + d], norm2F[d], s);
    den2F[tid] = s + EPSF;
  }

  const int hh = tid >> 5;
  const int ee = (tid & 31) * 2;
  float num2a = 0.f, num2b = 0.f;
  #pragma unroll
  for (int p = 0; p < 4; ++p) {
    const int ti = p >> 1, rh = p & 1;
    #pragma unroll
    for (int q = 0; q < 8; ++q) {
      const int rr = (q & 3) + 8*((q >> 2) & 1) + 4*g32;
      const int r = rh*8 + q;
      float v0 = (ti == 0) ? aD00[r] : aD10[r];
      float v1 = (ti == 0) ? aD01[r] : aD11[r];
      stageF[wave*1056 + rr*66 + c32]      = v0;
      stageF[wave*1056 + rr*66 + 32 + c32] = v1;
    }
    __syncthreads();
    #pragma unroll 8
    for (int dl = 0; dl < 16; ++dl) {
      float2 q0 = *(const float2*)&stageF[0*1056 + dl*66 + ee];
      float2 q1 = *(const float2*)&stageF[1*1056 + dl*66 + ee];
      float2 q2 = *(const float2*)&stageF[2*1056 + dl*66 + ee];
      float2 q3 = *(const float2*)&stageF[3*1056 + dl*66 + ee];
      float v0 = (q0.x + q1.x) + (q2.x + q3.x);
      float v1 = (q0.y + q1.y) + (q2.y + q3.y);
      float fv = fqg[hh*64 + p*16 + dl];
      num2a = fmaf(fv, v0, num2a);
      num2b = fmaf(fv, v1, num2b);
    }
    __syncthreads();
  }
  float rd2 = __builtin_amdgcn_rcpf(den2F[hh]);
  {
    uint32_t pa = packsplit(num2a * rd2);
    uint32_t pb = packsplit(num2b * rd2);
    const int w32 = b*256 + hh*32 + (ee >> 1);
    attnHi[w32] = __builtin_amdgcn_perm(pb, pa, SELHI);
    attnLo[w32] = __builtin_amdgcn_perm(pb, pa, SELLO);
  }
#undef ELEM
#undef QATAB_B
}

// =====================================================================
// Kernel 3: out = attn @ Wm + bm via MFMA. A-frags are direct uint4
//   loads from attnHi/Lo planes (k-contiguous). K-split x4 per block.
//   Grid 512 = 16 rt x 32 ct; block = 1 tile, 4 waves = 4 K-quarters.
// =====================================================================
__global__ __launch_bounds__(256) void out_mfma_kernel(
    const uint32_t* __restrict__ attnHi, const uint32_t* __restrict__ attnLo,
    const uint32_t* __restrict__ wmFrag, const float* __restrict__ bm,
    float* __restrict__ out)
{
  __shared__ float red[3][64][16];
  const int tid = threadIdx.x;
  const int wave = tid >> 6, lane = tid & 63;
  const int g32 = lane >> 5, c32 = lane & 31;
  const int rt = blockIdx.x >> 5, ct = blockIdx.x & 31;

  f32x16 acc;
  #pragma unroll
  for (int r = 0; r < 16; ++r) acc[r] = 0.f;

  const uint32_t* ah = attnHi + (size_t)(rt*32 + c32)*256 + g32*4;
  const uint32_t* al = attnLo + (size_t)(rt*32 + c32)*256 + g32*4;
  const uint32_t* wb = wmFrag + (size_t)ct*256 + lane*4;

  #pragma unroll
  for (int k8 = 0; k8 < 8; ++k8) {
    const int ks = wave*8 + k8;
    uint4 Ah = *(const uint4*)(ah + ks*8);
    uint4 Al = *(const uint4*)(al + ks*8);
    uint4 Bh = *(const uint4*)(wb + (size_t)(ks*2+0)*32*256);
    uint4 Bl = *(const uint4*)(wb + (size_t)(ks*2+1)*32*256);
    acc = mf(Ah, Bh, acc);
    acc = mf(Ah, Bl, acc);
    acc = mf(Al, Bh, acc);
  }

  if (wave) {
    #pragma unroll
    for (int r = 0; r < 16; ++r) red[wave-1][lane][r] = acc[r];
  }
  __syncthreads();
  if (wave == 0) {
    const int col = ct*32 + c32;
    const float bvv = bm[col];
    #pragma unroll
    for (int r = 0; r < 16; ++r) {
      const int m = rt*32 + (r & 3) + 8*(r >> 2) + 4*g32;
      float v = acc[r] + (red[0][lane][r] + red[1][lane][r]) + red[2][lane][r] + bvv;
      out[(size_t)m * 1024 + col] = v;
    }
  }
}

extern "C" void kernel_launch(void* const* d_in, const int* in_sizes, int n_in,
                              void* d_out, int out_size, void* d_ws, size_t ws_size,
                              hipStream_t stream)
{
  const float* x    = (const float*)d_in[0];
  const float* mem  = (const float*)d_in[1];
  const float* addr = (const float*)d_in[2];
  const float* Wk   = (const float*)d_in[3];
  const float* bk   = (const float*)d_in[4];
  const float* Wv   = (const float*)d_in[5];
  const float* bv   = (const float*)d_in[6];
  const float* Wq   = (const float*)d_in[7];
  const float* bq   = (const float*)d_in[8];
  const float* Wm   = (const float*)d_in[9];
  const float* bm   = (const float*)d_in[10];
  float* out  = (float*)d_out;
  float* ws   = (float*)d_ws;
  float* proj = ws;                                         // 4 MB
  uint32_t* qaF    = (uint32_t*)(proj + (size_t)512*2048);  // 0.5 MB
  uint32_t* wFrag  = qaF + 131072;                          // 8 MB
  uint32_t* xFrag  = wFrag + 2097152;                       // 2 MB
  uint32_t* wmFrag = xFrag + 524288;                        // 2 MB
  uint32_t* attnHi = wmFrag + 524288;                       // 0.5 MB
  uint32_t* attnLo = attnHi + 131072;                       // 0.5 MB

  hipLaunchKernelGGL(pack_all_kernel, dim3(6208), dim3(64), 0, stream,
                     addr, x, Wk, Wv, Wq, Wm, qaF, xFrag, wFrag, wmFrag);
  hipLaunchKernelGGL(proj_mfma_kernel, dim3(512), dim3(256), 0, stream,
                     xFrag, wFrag, bk, bv, bq, proj);
  hipLaunchKernelGGL(fused_mem_kernel, dim3(512), dim3(256), 0, stream,
                     mem, addr, proj, qaF, attnHi, attnLo);
  hipLaunchKernelGGL(out_mfma_kernel, dim3(512), dim3(256), 0, stream,
                     attnHi, attnLo, wmFrag, bm, out);
}

// Round 16
// 120.186 us; speedup vs baseline: 1.8160x; 1.0732x over previous
//
#include <hip/hip_runtime.h>
#include <hip/hip_bf16.h>
#include <math.h>

#define EPSF 1e-5f
#define SELHI 0x05040100u
#define SELLO 0x07060302u

typedef __attribute__((ext_vector_type(8))) short bf16x8;
typedef __attribute__((ext_vector_type(16))) float f32x16;

// pack float -> u32 { low16 = hi-bf16 (truncated), high16 = lo-bf16 (residual) }
__device__ __forceinline__ uint32_t packsplit(float x) {
  uint32_t xb = __builtin_bit_cast(uint32_t, x);
  float hi = __builtin_bit_cast(float, xb & 0xFFFF0000u);
  float resid = x - hi;
  return __builtin_amdgcn_perm(__builtin_bit_cast(uint32_t, resid), xb, 0x07060302u);
}

// float -> bf16 round-to-nearest-even (16-bit value in low bits)
__device__ __forceinline__ uint32_t bf16rne(float x) {
  uint32_t xb = __builtin_bit_cast(uint32_t, x);
  return (xb + 0x7FFFu + ((xb >> 16) & 1u)) >> 16;
}

__device__ __forceinline__ uint4 mkfrag8(const uint32_t* p, uint32_t sel) {
  uint4 u;
  u.x = __builtin_amdgcn_perm(p[1], p[0], sel);
  u.y = __builtin_amdgcn_perm(p[3], p[2], sel);
  u.z = __builtin_amdgcn_perm(p[5], p[4], sel);
  u.w = __builtin_amdgcn_perm(p[7], p[6], sel);
  return u;
}

__device__ __forceinline__ f32x16 mf(uint4 a, uint4 b, f32x16 c) {
  return __builtin_amdgcn_mfma_f32_32x32x16_bf16(
      __builtin_bit_cast(bf16x8, a), __builtin_bit_cast(bf16x8, b), c, 0, 0, 0);
}

#define F4C(v, i) ((i) == 0 ? (v).x : (i) == 1 ? (v).y : (i) == 2 ? (v).z : (v).w)

// =====================================================================
// Kernel 0: ALL fragment precomputes in ONE dispatch (flat grid 6208).
// =====================================================================
__global__ __launch_bounds__(64) void pack_all_kernel(
    const float* __restrict__ addresses,
    const float* __restrict__ x,
    const float* __restrict__ Wk, const float* __restrict__ Wv,
    const float* __restrict__ Wq, const float* __restrict__ Wm,
    uint32_t* __restrict__ qaF, uint32_t* __restrict__ xFrag,
    uint32_t* __restrict__ wFrag, uint32_t* __restrict__ wmFrag)
{
  const int bid = blockIdx.x;
  const int lane = threadIdx.x;
  const int g32 = lane >> 5, c32 = lane & 31;

  if (bid < 4096) {                       // ---- W pack
    const int kstep = bid >> 6, ct = bid & 63;
    const int col = ct*32 + c32;
    const float* Wp; int ldb, nc;
    if (col < 512)       { Wp = Wk; ldb = 512;  nc = col; }
    else if (col < 1536) { Wp = Wv; ldb = 1024; nc = col - 512; }
    else                 { Wp = Wq; ldb = 512;  nc = col - 1536; }
    uint32_t p[8];
    #pragma unroll
    for (int j = 0; j < 8; ++j)
      p[j] = packsplit(Wp[(size_t)(kstep*16 + g32*8 + j) * ldb + nc]);
    *(uint4*)&wFrag[((size_t)(kstep*2+0)*64 + ct)*256 + lane*4] = mkfrag8(p, SELHI);
    *(uint4*)&wFrag[((size_t)(kstep*2+1)*64 + ct)*256 + lane*4] = mkfrag8(p, SELLO);
  } else if (bid < 5120) {                // ---- x pack
    const int t = bid - 4096;
    const int kstep = t >> 4, rt = t & 15;
    const float* xp = x + (size_t)(rt*32 + c32)*1024 + kstep*16 + g32*8;
    float4 f0 = *(const float4*)xp;
    float4 f1 = *(const float4*)(xp + 4);
    uint32_t p[8] = { packsplit(f0.x), packsplit(f0.y), packsplit(f0.z), packsplit(f0.w),
                      packsplit(f1.x), packsplit(f1.y), packsplit(f1.z), packsplit(f1.w) };
    *(uint4*)&xFrag[((size_t)(kstep*2+0)*16 + rt)*256 + lane*4] = mkfrag8(p, SELHI);
    *(uint4*)&xFrag[((size_t)(kstep*2+1)*16 + rt)*256 + lane*4] = mkfrag8(p, SELLO);
  } else if (bid < 5184) {                // ---- qa pack
    const int T = bid - 5120;
    #pragma unroll
    for (int ks = 0; ks < 4; ++ks) {
      const float* ap = addresses + (size_t)(T*32 + c32)*64 + ks*16 + g32*8;
      float4 f0 = *(const float4*)ap;
      float4 f1 = *(const float4*)(ap + 4);
      uint32_t qp[8] = {
        packsplit(fmaxf(f0.x,0.f)), packsplit(fmaxf(f0.y,0.f)),
        packsplit(fmaxf(f0.z,0.f)), packsplit(fmaxf(f0.w,0.f)),
        packsplit(fmaxf(f1.x,0.f)), packsplit(fmaxf(f1.y,0.f)),
        packsplit(fmaxf(f1.z,0.f)), packsplit(fmaxf(f1.w,0.f)) };
      *(uint4*)&qaF[(size_t)T*2048 + (ks*2+0)*256 + lane*4] = mkfrag8(qp, SELHI);
      *(uint4*)&qaF[(size_t)T*2048 + (ks*2+1)*256 + lane*4] = mkfrag8(qp, SELLO);
    }
  } else {                                // ---- Wm pack
    const int t = bid - 5184;
    const int ks = t >> 5, ct = t & 31;
    const int col = ct*32 + c32;
    uint32_t p[8];
    #pragma unroll
    for (int j = 0; j < 8; ++j)
      p[j] = packsplit(Wm[(size_t)(ks*16 + g32*8 + j) * 1024 + col]);
    *(uint4*)&wmFrag[((size_t)(ks*2+0)*32 + ct)*256 + lane*4] = mkfrag8(p, SELHI);
    *(uint4*)&wmFrag[((size_t)(ks*2+1)*32 + ct)*256 + lane*4] = mkfrag8(p, SELLO);
  }
}

// =====================================================================
// Kernel 1: proj via MFMA, K-split x2 (unchanged from R14).
// =====================================================================
__global__ __launch_bounds__(256) void proj_mfma_kernel(
    const uint32_t* __restrict__ xFrag, const uint32_t* __restrict__ wFrag,
    const float* __restrict__ bk, const float* __restrict__ bv,
    const float* __restrict__ bq, float* __restrict__ proj)
{
  __shared__ float red[2][64][16];
  const int tid = threadIdx.x;
  const int wave = tid >> 6, lane = tid & 63;
  const int g32 = lane >> 5, c32 = lane & 31;
  const int tile = blockIdx.x*2 + (wave & 1);
  const int khalf = wave >> 1;
  const int rt = tile >> 6, ct = tile & 63;

  f32x16 acc;
  #pragma unroll
  for (int r = 0; r < 16; ++r) acc[r] = 0.f;

  const uint32_t* xb = xFrag + (size_t)rt*256 + lane*4;
  const uint32_t* wb = wFrag + (size_t)ct*256 + lane*4;

  #pragma unroll 2
  for (int k8 = 0; k8 < 32; ++k8) {
    const int ks = khalf*32 + k8;
    uint4 Ah = *(const uint4*)(xb + (size_t)(ks*2+0)*16*256);
    uint4 Al = *(const uint4*)(xb + (size_t)(ks*2+1)*16*256);
    uint4 Bh = *(const uint4*)(wb + (size_t)(ks*2+0)*64*256);
    uint4 Bl = *(const uint4*)(wb + (size_t)(ks*2+1)*64*256);
    acc = mf(Ah, Bh, acc);
    acc = mf(Ah, Bl, acc);
    acc = mf(Al, Bh, acc);
  }

  if (khalf == 1) {
    #pragma unroll
    for (int r = 0; r < 16; ++r) red[wave & 1][lane][r] = acc[r];
  }
  __syncthreads();
  if (khalf == 0) {
    const int col = ct*32 + c32;
    const float* bias; int nc, relu;
    if (col < 512)       { bias = bk; nc = col;        relu = 1; }
    else if (col < 1536) { bias = bv; nc = col - 512;  relu = 0; }
    else                 { bias = bq; nc = col - 1536; relu = 1; }
    const float bvv = bias[nc];
    #pragma unroll
    for (int r = 0; r < 16; ++r) {
      const int m = rt*32 + (r & 3) + 8*(r >> 2) + 4*g32;
      float v = acc[r] + red[wave & 1][lane][r] + bvv;
      if (relu) v = fmaxf(v, 0.f);
      proj[(size_t)m * 2048 + col] = v;
    }
  }
}

// =====================================================================
// Kernel 2: fused memory kernel, R15.
//   vs R14: qa fragments for the NEXT superstep staged into per-wave
//   LDS slots via global_load_lds (no VGPR round-trip); phase 3 reads
//   pure LDS. pk tiles [32][68]->[32][64] u16 + XOR swizzle
//   (col ^= (row&7)<<3) to fit the 80 KB / 2-blocks-per-CU budget.
//   Ordering: glLDS(ss+2) issued before ELEM(ss)'s E_ loads; in-order
//   vmcnt retire means existing E_ waits guarantee qa completion one
//   full superstep before consumption.
// =====================================================================
__global__ __launch_bounds__(256, 2) void fused_mem_kernel(
    const float* __restrict__ memories,   // [512][2048][64]
    const float* __restrict__ addresses,  // [2048][64]
    const float* __restrict__ proj,       // [512][2048] = fk|v|fq
    const uint32_t* __restrict__ qaF,     // [64][8][64][4] qa fragments
    uint32_t* __restrict__ attnHi,        // [512][256] u32
    uint32_t* __restrict__ attnLo)        // [512][256]
{
  // 80 KB arena (u32 indices):
  //  [0,2048)       fkFrag        (epilogue: n2stage/norm2/den2 overlay)
  //  [2048,4096)    vFrag
  //  [4096,12288)   pk: 4 waves x { pF16[32][64], pN16[32][64] } u16
  //  [12288,20480)  qabuf: 4 waves x 2048 u32 (8 KB qa staging)
  //  (pbuf staging overlays pk at start; stageF overlays pk+qabuf at end)
  __shared__ uint32_t SH[20480];

  const int b = blockIdx.x, tid = threadIdx.x;
  const int wave = tid >> 6, lane = tid & 63;
  const int g32 = lane >> 5, c32 = lane & 31;

  uint32_t* fkFrag = SH;
  uint32_t* vFrag  = SH + 2048;
  uint32_t* pkbase = SH + 4096;
  unsigned short* pF16 = (unsigned short*)(pkbase + wave * 2048);  // [32][64]
  unsigned short* pN16 = pF16 + 2048;
  uint32_t* qabuf = SH + 12288 + wave * 2048;

  // ---- stage proj row (pbuf overlays pk region) ----
  float* pbuf = (float*)pkbase;
  {
    const float* prow = proj + (size_t)b * 2048;
    *(float4*)&pbuf[tid*8]   = *(const float4*)&prow[tid*8];
    *(float4*)&pbuf[tid*8+4] = *(const float4*)&prow[tid*8+4];
  }
  __syncthreads();

  // ---- one-time fragment packing (wave w: kstep w, e-tile w) ----
  {
    const int ks = wave;
    float4 f0 = *(const float4*)&pbuf[c32*64 + ks*16 + g32*8];
    float4 f1 = *(const float4*)&pbuf[c32*64 + ks*16 + g32*8 + 4];
    uint32_t p[8] = { packsplit(f0.x), packsplit(f0.y), packsplit(f0.z), packsplit(f0.w),
                      packsplit(f1.x), packsplit(f1.y), packsplit(f1.z), packsplit(f1.w) };
    *(uint4*)&fkFrag[((ks*2+0)*64 + lane)*4] = mkfrag8(p, SELHI);
    *(uint4*)&fkFrag[((ks*2+1)*64 + lane)*4] = mkfrag8(p, SELLO);
    const int t = wave;
    uint32_t q[8];
    #pragma unroll
    for (int j = 0; j < 8; ++j) {
      int h = (g32*8 + j) & 7;
      q[j] = packsplit(pbuf[512 + h*128 + t*32 + c32]);
    }
    *(uint4*)&vFrag[((t*2+0)*64 + lane)*4] = mkfrag8(q, SELHI);
    *(uint4*)&vFrag[((t*2+1)*64 + lane)*4] = mkfrag8(q, SELLO);
  }
  __syncthreads();

  f32x16 Zv;
  #pragma unroll
  for (int r = 0; r < 16; ++r) Zv[r] = 0.f;
  f32x16 aD00 = Zv, aD01 = Zv, aD10 = Zv, aD11 = Zv;
  float n2a[32];
  #pragma unroll
  for (int k = 0; k < 32; ++k) n2a[k] = 0.f;

  const float* aRow0 = addresses + (size_t)(wave*512 + c32) * 64;
  const float* mRow0 = memories + ((size_t)b*2048 + wave*512 + c32) * 64;

  // stage qa fragments for tile T into this wave's LDS slot (no VGPRs)
  auto stage_qa = [&](int T) {
    const uint32_t* src = qaF + (size_t)T*2048 + lane*4;
    #pragma unroll
    for (int j = 0; j < 8; ++j)
      __builtin_amdgcn_global_load_lds(
        (const __attribute__((address_space(1))) uint32_t*)(src + j*256),
        (__attribute__((address_space(3))) uint32_t*)(qabuf + j*256), 16, 0, 0);
    asm volatile("" ::: "memory");
  };

  // phase D: single-bf16 operands from XOR-swizzled [32][64] u16 tiles.
  auto do_mfma = [&](int base) {
    uint32_t f0[4], f1[4], n0[4], n1[4];
    #pragma unroll
    for (int e = 0; e < 4; ++e) {
      const int ra = base + g32*8 + 2*e, rb = ra + 1;
      const int sa = (ra & 7) << 3, sb = (rb & 7) << 3;
      const int a0 = ra*64 + (c32 ^ sa),        b0 = rb*64 + (c32 ^ sb);
      const int a1 = ra*64 + ((32 + c32) ^ sa), b1 = rb*64 + ((32 + c32) ^ sb);
      f0[e] = (uint32_t)pF16[a0] | ((uint32_t)pF16[b0] << 16);
      f1[e] = (uint32_t)pF16[a1] | ((uint32_t)pF16[b1] << 16);
      n0[e] = (uint32_t)pN16[a0] | ((uint32_t)pN16[b0] << 16);
      n1[e] = (uint32_t)pN16[a1] | ((uint32_t)pN16[b1] << 16);
    }
    uint4 A0 = make_uint4(f0[0], f0[1], f0[2], f0[3]);
    uint4 A1 = make_uint4(f1[0], f1[1], f1[2], f1[3]);
    uint4 B0 = make_uint4(n0[0], n0[1], n0[2], n0[3]);
    uint4 B1 = make_uint4(n1[0], n1[1], n1[2], n1[3]);
    aD00 = mf(A0, B0, aD00);
    aD01 = mf(A0, B1, aD01);
    aD10 = mf(A1, B0, aD10);
    aD11 = mf(A1, B1, aD11);
  };

  // B-MFMAs consuming the LDS-staged qa fragments (pure LDS reads)
#define QALDS_B(ACC) do {                                              \
    _Pragma("unroll")                                                  \
    for (int ks = 0; ks < 4; ++ks) {                                   \
      uint4 qh_ = *(uint4*)&qabuf[(ks*2+0)*256 + lane*4];              \
      uint4 ql_ = *(uint4*)&qabuf[(ks*2+1)*256 + lane*4];              \
      uint4 Ah_ = *(uint4*)&fkFrag[((ks*2+0)*64 + lane)*4];            \
      uint4 Al_ = *(uint4*)&fkFrag[((ks*2+1)*64 + lane)*4];            \
      ACC = mf(Ah_, qh_, ACC); ACC = mf(Ah_, ql_, ACC); ACC = mf(Al_, qh_, ACC); \
    } } while(0)

#define ELEM(T2, ACU, ACW) do {                                        \
    unsigned short* rowF_ = pF16 + c32*64;                             \
    unsigned short* rowN_ = pN16 + c32*64;                             \
    const int sx_ = (c32 & 7) << 3;                                    \
    _Pragma("unroll")                                                  \
    for (int rq = 0; rq < 4; ++rq) {                                   \
      uint32_t pf_[4], pn_[4];                                         \
      _Pragma("unroll")                                                \
      for (int i = 0; i < 4; ++i) {                                    \
        const int r = rq*4 + i;                                        \
        float upd = ACU[r];                                            \
        float wx  = ACW[r];                                            \
        float wp  = __builtin_amdgcn_rcpf(1.f + __expf(-wx));          \
        float mv  = F4C(M_[(T2)*4 + rq], i);                           \
        float av  = F4C(E_[rq & 1], i);                                \
        float nm  = fmaf(wp, upd - mv, mv);                            \
        float fv  = fmaxf(nm + av, 0.f);                               \
        n2a[(T2)*16 + r] += fv;                                        \
        pn_[i] = bf16rne(nm);                                          \
        pf_[i] = bf16rne(fv);                                          \
      }                                                                \
      if (rq == 1) { E_[0] = *(const float4*)(ap0 + (T2)*32 + 16 + g32*4);      \
                     E_[1] = *(const float4*)(ap0 + (T2)*32 + 16 + g32*4 + 8); }\
      const int col = (32*(T2) + 8*rq + 4*g32) ^ sx_;                  \
      *(uint2*)&rowF_[col] = make_uint2(pf_[0] | (pf_[1]<<16), pf_[2] | (pf_[3]<<16)); \
      *(uint2*)&rowN_[col] = make_uint2(pn_[0] | (pn_[1]<<16), pn_[2] | (pn_[3]<<16)); \
    } } while(0)

  // ---- prologue: stage qa(0), B(0), stage qa(1), M(0) ----
  f32x16 aBcur = Zv, aBnext;
  float4 M_[8];
  stage_qa(wave*16 + 0);
  asm volatile("s_waitcnt vmcnt(0)" ::: "memory");
  __builtin_amdgcn_sched_barrier(0);
  QALDS_B(aBcur);
  stage_qa(wave*16 + 1);
  #pragma unroll
  for (int k = 0; k < 8; ++k) M_[k] = *(const float4*)(mRow0 + k*8 + g32*4);

  #pragma unroll 1
  for (int ss = 0; ss < 16; ++ss) {
    asm volatile("" ::: "memory");

    // ---- 1. finish B(ss): S, den; rden folded into S-fragment ----
    float s0 = aBcur[0], s1 = aBcur[1], s2 = aBcur[2], s3 = aBcur[3];
    float own = (s0 + s1) + (s2 + s3);
    float den = own + __shfl_xor(own, 32) + EPSF;
    float rden = __builtin_amdgcn_rcpf(den);
    float p0 = __shfl_xor(s0, 32), p1 = __shfl_xor(s1, 32),
          p2 = __shfl_xor(s2, 32), p3 = __shfl_xor(s3, 32);
    float rm = (g32 == 0) ? rden : 0.f;
    uint32_t sp[8] = { packsplit(s0*rm), packsplit(s1*rm), packsplit(s2*rm), packsplit(s3*rm),
                       packsplit(p0*rm), packsplit(p1*rm), packsplit(p2*rm), packsplit(p3*rm) };
    uint4 Sh = mkfrag8(sp, SELHI), Sl = mkfrag8(sp, SELLO);

    // ---- 2. C-MFMAs, first half (e-tiles 0 and 2) ----
    f32x16 aC0 = Zv, aC2 = Zv;
    {
      uint4 Vh, Vl;
      Vh = *(uint4*)&vFrag[(0*64 + lane)*4]; Vl = *(uint4*)&vFrag[(1*64 + lane)*4];
      aC0 = mf(Vh, Sh, aC0); aC0 = mf(Vh, Sl, aC0); aC0 = mf(Vl, Sh, aC0);
      Vh = *(uint4*)&vFrag[(4*64 + lane)*4]; Vl = *(uint4*)&vFrag[(5*64 + lane)*4];
      aC2 = mf(Vh, Sh, aC2); aC2 = mf(Vh, Sl, aC2); aC2 = mf(Vl, Sh, aC2);
    }

    // ---- 3. pipeline: B(ss+1) from LDS-staged qa; then stage qa(ss+2) ----
    aBnext = Zv;
    if (ss < 15) QALDS_B(aBnext);
    if (ss < 14) stage_qa(wave*16 + ss + 2);

    // ---- 4. ELEM half 0 (lazy E loads; issued AFTER glLDS -> their
    //         waits imply qa staging completion, in-order vmcnt) ----
    const float* ap0 = aRow0 + (size_t)ss * 2048;
    float4 E_[2];
    E_[0] = *(const float4*)(ap0 + g32*4);
    E_[1] = *(const float4*)(ap0 + g32*4 + 8);
    ELEM(0, aC0, aC2);

    // ---- 5. C-MFMAs, second half (e-tiles 1 and 3) ----
    f32x16 aC1 = Zv, aC3 = Zv;
    {
      uint4 Vh, Vl;
      Vh = *(uint4*)&vFrag[(2*64 + lane)*4]; Vl = *(uint4*)&vFrag[(3*64 + lane)*4];
      aC1 = mf(Vh, Sh, aC1); aC1 = mf(Vh, Sl, aC1); aC1 = mf(Vl, Sh, aC1);
      Vh = *(uint4*)&vFrag[(6*64 + lane)*4]; Vl = *(uint4*)&vFrag[(7*64 + lane)*4];
      aC3 = mf(Vh, Sh, aC3); aC3 = mf(Vh, Sl, aC3); aC3 = mf(Vl, Sh, aC3);
    }

    // ---- 6. M_[0..3] <- ss+1 (HBM stream) ----
    if (ss < 15) {
      const float* mp = mRow0 + (size_t)(ss+1) * 2048;
      #pragma unroll
      for (int k = 0; k < 4; ++k) M_[k] = *(const float4*)(mp + k*8 + g32*4);
    }

    // ---- 7. ELEM half 1 ----
    E_[0] = *(const float4*)(ap0 + 32 + g32*4);
    E_[1] = *(const float4*)(ap0 + 32 + g32*4 + 8);
    ELEM(1, aC1, aC3);

    // ---- 8. M_[4..7] <- ss+1 ----
    if (ss < 15) {
      const float* mp = mRow0 + (size_t)(ss+1) * 2048;
      #pragma unroll
      for (int k = 4; k < 8; ++k) M_[k] = *(const float4*)(mp + k*8 + g32*4);
    }

    // ---- 9. phase D: both 16-row chunks (DS + MFMA only) ----
    asm volatile("" ::: "memory");
    do_mfma(0);
    do_mfma(16);

    aBcur = aBnext;
  }

  // ================= epilogue =================
  __syncthreads();

  float* n2stageF = (float*)SH;            // [4][64]
  float* norm2F   = ((float*)SH) + 256;    // [64]
  float* den2F    = ((float*)SH) + 320;    // [8]
  float* stageF   = (float*)pkbase;        // [4][16][66] (pk+qa overlay)
  const float* fqg = proj + (size_t)b * 2048 + 1536;

  #pragma unroll
  for (int k = 0; k < 32; ++k) {
    float v = n2a[k];
    v += __shfl_xor(v, 1); v += __shfl_xor(v, 2); v += __shfl_xor(v, 4);
    v += __shfl_xor(v, 8); v += __shfl_xor(v, 16);
    n2a[k] = v;
  }
  if (c32 == 0) {
    #pragma unroll
    for (int t2 = 0; t2 < 2; ++t2)
      #pragma unroll
      for (int r = 0; r < 16; ++r) {
        const int j = 32*t2 + 8*(r>>2) + (r&3) + 4*g32;
        n2stageF[wave*64 + j] = n2a[t2*16 + r];
      }
  }
  __syncthreads();
  if (tid < 64)
    norm2F[tid] = (n2stageF[tid] + n2stageF[64+tid]) + (n2stageF[128+tid] + n2stageF[192+tid]);
  __syncthreads();
  if (tid < 8) {
    float s = 0.f;
    for (int d = 0; d < 64; ++d) s = fmaf(fqg[tid*64 + d], norm2F[d], s);
    den2F[tid] = s + EPSF;
  }

  const int hh = tid >> 5;
  const int ee = (tid & 31) * 2;
  float num2a = 0.f, num2b = 0.f;
  #pragma unroll
  for (int p = 0; p < 4; ++p) {
    const int ti = p >> 1, rh = p & 1;
    #pragma unroll
    for (int q = 0; q < 8; ++q) {
      const int rr = (q & 3) + 8*((q >> 2) & 1) + 4*g32;
      const int r = rh*8 + q;
      float v0 = (ti == 0) ? aD00[r] : aD10[r];
      float v1 = (ti == 0) ? aD01[r] : aD11[r];
      stageF[wave*1056 + rr*66 + c32]      = v0;
      stageF[wave*1056 + rr*66 + 32 + c32] = v1;
    }
    __syncthreads();
    #pragma unroll 8
    for (int dl = 0; dl < 16; ++dl) {
      float2 q0 = *(const float2*)&stageF[0*1056 + dl*66 + ee];
      float2 q1 = *(const float2*)&stageF[1*1056 + dl*66 + ee];
      float2 q2 = *(const float2*)&stageF[2*1056 + dl*66 + ee];
      float2 q3 = *(const float2*)&stageF[3*1056 + dl*66 + ee];
      float v0 = (q0.x + q1.x) + (q2.x + q3.x);
      float v1 = (q0.y + q1.y) + (q2.y + q3.y);
      float fv = fqg[hh*64 + p*16 + dl];
      num2a = fmaf(fv, v0, num2a);
      num2b = fmaf(fv, v1, num2b);
    }
    __syncthreads();
  }
  float rd2 = __builtin_amdgcn_rcpf(den2F[hh]);
  {
    uint32_t pa = packsplit(num2a * rd2);
    uint32_t pb = packsplit(num2b * rd2);
    const int w32 = b*256 + hh*32 + (ee >> 1);
    attnHi[w32] = __builtin_amdgcn_perm(pb, pa, SELHI);
    attnLo[w32] = __builtin_amdgcn_perm(pb, pa, SELLO);
  }
#undef ELEM
#undef QALDS_B
}

// =====================================================================
// Kernel 3: out = attn @ Wm + bm via MFMA (unchanged from R14).
// =====================================================================
__global__ __launch_bounds__(256) void out_mfma_kernel(
    const uint32_t* __restrict__ attnHi, const uint32_t* __restrict__ attnLo,
    const uint32_t* __restrict__ wmFrag, const float* __restrict__ bm,
    float* __restrict__ out)
{
  __shared__ float red[3][64][16];
  const int tid = threadIdx.x;
  const int wave = tid >> 6, lane = tid & 63;
  const int g32 = lane >> 5, c32 = lane & 31;
  const int rt = blockIdx.x >> 5, ct = blockIdx.x & 31;

  f32x16 acc;
  #pragma unroll
  for (int r = 0; r < 16; ++r) acc[r] = 0.f;

  const uint32_t* ah = attnHi + (size_t)(rt*32 + c32)*256 + g32*4;
  const uint32_t* al = attnLo + (size_t)(rt*32 + c32)*256 + g32*4;
  const uint32_t* wb = wmFrag + (size_t)ct*256 + lane*4;

  #pragma unroll
  for (int k8 = 0; k8 < 8; ++k8) {
    const int ks = wave*8 + k8;
    uint4 Ah = *(const uint4*)(ah + ks*8);
    uint4 Al = *(const uint4*)(al + ks*8);
    uint4 Bh = *(const uint4*)(wb + (size_t)(ks*2+0)*32*256);
    uint4 Bl = *(const uint4*)(wb + (size_t)(ks*2+1)*32*256);
    acc = mf(Ah, Bh, acc);
    acc = mf(Ah, Bl, acc);
    acc = mf(Al, Bh, acc);
  }

  if (wave) {
    #pragma unroll
    for (int r = 0; r < 16; ++r) red[wave-1][lane][r] = acc[r];
  }
  __syncthreads();
  if (wave == 0) {
    const int col = ct*32 + c32;
    const float bvv = bm[col];
    #pragma unroll
    for (int r = 0; r < 16; ++r) {
      const int m = rt*32 + (r & 3) + 8*(r >> 2) + 4*g32;
      float v = acc[r] + (red[0][lane][r] + red[1][lane][r]) + red[2][lane][r] + bvv;
      out[(size_t)m * 1024 + col] = v;
    }
  }
}

extern "C" void kernel_launch(void* const* d_in, const int* in_sizes, int n_in,
                              void* d_out, int out_size, void* d_ws, size_t ws_size,
                              hipStream_t stream)
{
  const float* x    = (const float*)d_in[0];
  const float* mem  = (const float*)d_in[1];
  const float* addr = (const float*)d_in[2];
  const float* Wk   = (const float*)d_in[3];
  const float* bk   = (const float*)d_in[4];
  const float* Wv   = (const float*)d_in[5];
  const float* bv   = (const float*)d_in[6];
  const float* Wq   = (const float*)d_in[7];
  const float* bq   = (const float*)d_in[8];
  const float* Wm   = (const float*)d_in[9];
  const float* bm   = (const float*)d_in[10];
  float* out  = (float*)d_out;
  float* ws   = (float*)d_ws;
  float* proj = ws;                                         // 4 MB
  uint32_t* qaF    = (uint32_t*)(proj + (size_t)512*2048);  // 0.5 MB
  uint32_t* wFrag  = qaF + 131072;                          // 8 MB
  uint32_t* xFrag  = wFrag + 2097152;                       // 2 MB
  uint32_t* wmFrag = xFrag + 524288;                        // 2 MB
  uint32_t* attnHi = wmFrag + 524288;                       // 0.5 MB
  uint32_t* attnLo = attnHi + 131072;                       // 0.5 MB

  hipLaunchKernelGGL(pack_all_kernel, dim3(6208), dim3(64), 0, stream,
                     addr, x, Wk, Wv, Wq, Wm, qaF, xFrag, wFrag, wmFrag);
  hipLaunchKernelGGL(proj_mfma_kernel, dim3(512), dim3(256), 0, stream,
                     xFrag, wFrag, bk, bv, bq, proj);
  hipLaunchKernelGGL(fused_mem_kernel, dim3(512), dim3(256), 0, stream,
                     mem, addr, proj, qaF, attnHi, attnLo);
  hipLaunchKernelGGL(out_mfma_kernel, dim3(512), dim3(256), 0, stream,
                     attnHi, attnLo, wmFrag, bm, out);
}